// Round 11
// baseline (96.425 us; speedup 1.0000x reference)
//
#include <hip/hip_runtime.h>
#include <hip/hip_bf16.h>

// LocalCausalAttention: B=2, N=2048, D=1024, H=16, DH=64, WINDOW=64
// out = ( softmax(mask(QK^T*0.125)) V ) Wout^T + bout,  QKV = x Wqkv^T + bqkv
//
// R11: BARRIER-FREE single-wave GEMM. Evidence: R1-R10 all land 46-52us for QKV
//   (2-barrier-per-step family is latency-floor-bound; L2 traffic and VALU work
//   both exonerated by direct measurement). The never-removed component is the
//   per-step 2x s_barrier convoy. Remove it structurally:
//   - 64-thread (1-wave) workgroups, per-wave 64x64 output, BK=32, private 16KB
//     LDS double-buffer -> NO s_barrier anywhere in the kernel.
//   - per step t: {8 ds_read_b128 ; 16 MFMA ; lgkmcnt(0)+sched_barrier ;
//     stage tile t+2 into buf[t&1] (8 gloads) ; vmcnt(8)}  (counted, never 0
//     until the tail; WAR safe by in-wave ordering, RAW by vmcnt ledger)
//   - 10 blocks/CU co-resident (LDS-bound), fully decorrelated chains.
//   - cost: B not shared across waves -> ~768MB L2 staging (~22us at L2 ceiling)
//     = the new bound, below the old ~46us barrier floor.
//   QKV grid 3072 (2D 16m x 24n per XCD), outproj grid 1024 (16m x 8n per XCD).
//   Q/K scatter + V-LDS-transpose epilogues (R8-verified) carried over.

typedef __attribute__((ext_vector_type(8))) __bf16 bf16x8;
typedef __attribute__((ext_vector_type(4))) float f32x4;

#define GLOAD16(g, l)                                              \
  __builtin_amdgcn_global_load_lds(                                \
      (const __attribute__((address_space(1))) void*)(g),          \
      (__attribute__((address_space(3))) void*)(l), 16, 0, 0)

#define MFMA16(a, b, c) __builtin_amdgcn_mfma_f32_16x16x32_bf16((a), (b), (c), 0, 0, 0)

// ---------------- fused fp32 -> bf16 convert (x, Wqkv, Wout) ----------------
__global__ __launch_bounds__(256) void cvt3(const float* __restrict__ x,
                                            const float* __restrict__ wqkv,
                                            const float* __restrict__ wout,
                                            __bf16* __restrict__ xb,
                                            __bf16* __restrict__ wqkvb,
                                            __bf16* __restrict__ woutb) {
  const int blk = blockIdx.x;
  const float* src;
  __bf16* dst;
  int i;
  if (blk < 2048) {            // x: 4194304 elems
    src = x; dst = xb; i = (blk * 256 + (int)threadIdx.x) * 8;
  } else if (blk < 3584) {     // Wqkv: 3145728 elems
    src = wqkv; dst = wqkvb; i = ((blk - 2048) * 256 + (int)threadIdx.x) * 8;
  } else {                     // Wout: 1048576 elems
    src = wout; dst = woutb; i = ((blk - 3584) * 256 + (int)threadIdx.x) * 8;
  }
  f32x4 a = *(const f32x4*)(src + i);
  f32x4 b = *(const f32x4*)(src + i + 4);
  bf16x8 o;
  o[0] = (__bf16)a[0]; o[1] = (__bf16)a[1]; o[2] = (__bf16)a[2]; o[3] = (__bf16)a[3];
  o[4] = (__bf16)b[0]; o[5] = (__bf16)b[1]; o[6] = (__bf16)b[2]; o[7] = (__bf16)b[3];
  *(bf16x8*)(dst + i) = o;
}

// ---------------- barrier-free single-wave 64x64 GEMM ----------------
// C[m,n] = sum_k A[m,k]*Bw[n,k] + bias[n]; K=1024 fixed.
// MODE 0: QKV (M=4096,N=3072): scatter Q(*0.125)/K; V via LDS-transpose -> Vt.
// MODE 1: out-proj (M=4096,N=1024): fp32 out + bias.
// RN = per-XCD rectangle n-count (XCD rect = 16m x RN n, grid = 8*16*RN blocks).
template <int MODE, int RN>
__global__ __launch_bounds__(64) void gemm_sw(
    const __bf16* __restrict__ A, const __bf16* __restrict__ Bw,
    const float* __restrict__ bias,
    float* __restrict__ outF,
    __bf16* __restrict__ qo, __bf16* __restrict__ ko, __bf16* __restrict__ vt) {
  constexpr int K = 1024;
  __shared__ __align__(16) unsigned char Ls[16384];  // [buf0: A 4K | B 4K][buf1: ...]
  const int lane = (int)threadIdx.x;
  const int colL = lane & 15, g = lane >> 4;

  // 2D per-XCD rectangle (bijective): xcd owns 16m x RN n tiles of 64x64
  const int xcd = (int)blockIdx.x & 7;
  const int i = (int)blockIdx.x >> 3;
  const int mR = (xcd >> 1) * 16 + i / RN;
  const int nR = (xcd & 1) * RN + i % RN;
  const int m0 = mR * 64, n0 = nR * 64;

  const __bf16* Ap = A + (size_t)m0 * K;
  const __bf16* Bp = Bw + (size_t)n0 * K;

  // stage 64 rows x 32 cols = 4KB (paired-row layout, R6-verified 0-conflict):
  // chunk c: line L=c>>3, s6=c&7; u=s6^(L&7) -> src row=2L+(u>>2), col8 p=u&3.
  auto stg = [&](const __bf16* src, unsigned char* lds, int k0) {
#pragma unroll
    for (int it = 0; it < 4; ++it) {
      int c = lane + (it << 6);       // 0..255
      int L = c >> 3, s6 = c & 7;
      int u = s6 ^ (L & 7);
      int row = (L << 1) | (u >> 2), p = u & 3;
      GLOAD16(src + (size_t)row * K + k0 + (p << 3), lds + c * 16);
    }
  };

  f32x4 acc[4][4] = {};

  // prologue: tile0 -> buf0, tile1 -> buf1 (8 gloads each)
  stg(Ap, Ls, 0);
  stg(Bp, Ls + 4096, 0);
  stg(Ap, Ls + 8192, 32);
  stg(Bp, Ls + 12288, 32);
  asm volatile("s_waitcnt vmcnt(8)" ::: "memory");  // tile0 landed; tile1 in flight

  for (int t = 0; t < 32; ++t) {
    const unsigned char* Ab = Ls + (t & 1) * 8192;
    const unsigned char* Bb = Ab + 4096;
    bf16x8 af[4], bf[4];
#pragma unroll
    for (int mi = 0; mi < 4; ++mi) {
      const int r = (mi << 4) + colL;
      af[mi] = *(const bf16x8*)(Ab + (r >> 1) * 128 +
                                (((((r & 1) << 2) | g) ^ ((r >> 1) & 7)) << 4));
    }
#pragma unroll
    for (int ni = 0; ni < 4; ++ni) {
      const int r = (ni << 4) + colL;
      bf[ni] = *(const bf16x8*)(Bb + (r >> 1) * 128 +
                                (((((r & 1) << 2) | g) ^ ((r >> 1) & 7)) << 4));
    }
#pragma unroll
    for (int mi = 0; mi < 4; ++mi)
#pragma unroll
      for (int ni = 0; ni < 4; ++ni)
        acc[mi][ni] = MFMA16(af[mi], bf[ni], acc[mi][ni]);
    if (t < 30) {
      // WAR: this wave's ds_reads of buf[t&1] must complete before the DMA
      // overwrites it (in-wave ordering; sched_barrier pins the gloads below).
      asm volatile("s_waitcnt lgkmcnt(0)" ::: "memory");
      __builtin_amdgcn_sched_barrier(0);
      unsigned char* d = Ls + (t & 1) * 8192;
      const int kn = (t + 2) << 5;
      stg(Ap, d, kn);
      stg(Bp, d + 4096, kn);
      // in flight: tile t+1 (8) + t+2 (8); retire oldest 8 -> t+1 validated
      asm volatile("s_waitcnt vmcnt(8)" ::: "memory");
    } else if (t == 30) {
      asm volatile("s_waitcnt vmcnt(0)" ::: "memory");  // tail: tile 31 landed
    }
  }

  // epilogue: C/D layout col=lane&15, row=(lane>>4)*4+reg (m89-verified)
  if (MODE == 0) {
    const int sx = n0 >> 10, h = (n0 >> 6) & 15;   // block's 64 cols: one head
    float bv[4];
#pragma unroll
    for (int ni = 0; ni < 4; ++ni) bv[ni] = bias[n0 + (ni << 4) + colL];
    const int b = m0 >> 11, tt0 = m0 & 2047;
    if (sx == 2) {
      // ---- V: transpose via LDS (loop-free region), coalesced rows of Vt ----
      unsigned char* wreg = Ls;                    // [64][72] bf16 = 9216B
#pragma unroll
      for (int mi = 0; mi < 4; ++mi)
#pragma unroll
        for (int ni = 0; ni < 4; ++ni)
#pragma unroll
          for (int jp = 0; jp < 2; ++jp) {
            const int tt = (mi << 4) + (g << 2) + (jp << 1);
            const int d = (ni << 4) + colL;
            unsigned short u0 = __builtin_bit_cast(
                unsigned short, (__bf16)(acc[mi][ni][jp * 2] + bv[ni]));
            unsigned short u1 = __builtin_bit_cast(
                unsigned short, (__bf16)(acc[mi][ni][jp * 2 + 1] + bv[ni]));
            *(unsigned int*)(wreg + ((d * 72 + tt) << 1)) =
                (unsigned int)u0 | ((unsigned int)u1 << 16);
          }
      asm volatile("s_waitcnt lgkmcnt(0)" ::: "memory");
      const size_t vbase = (size_t)(b * 16 + h) * 64 * 2048;
#pragma unroll
      for (int i2 = 0; i2 < 32; ++i2) {
        const int d = (i2 << 1) + (lane >> 5);
        const int toff = (lane & 31) << 1;
        unsigned int v = *(unsigned int*)(wreg + (d * 144 + ((lane & 31) << 2)));
        *(unsigned int*)((unsigned short*)vt + vbase + (size_t)d * 2048 + tt0 + toff) = v;
      }
    } else {
      __bf16* dst = (sx == 0) ? qo : ko;
      const float mul = (sx == 0) ? 0.125f : 1.0f;  // fold SCALE into Q (exact pow2)
#pragma unroll
      for (int mi = 0; mi < 4; ++mi) {
#pragma unroll
        for (int j = 0; j < 4; ++j) {
          const int tt = tt0 + (mi << 4) + (g << 2) + j;
          __bf16* rowp = dst + (((size_t)b * 16 + h) * 2048 + tt) * 64;
#pragma unroll
          for (int ni = 0; ni < 4; ++ni)  // 4 x 32B bursts -> full 128B line
            rowp[(ni << 4) + colL] = (__bf16)((acc[mi][ni][j] + bv[ni]) * mul);
        }
      }
    }
  } else {
    float bv[4];
#pragma unroll
    for (int ni = 0; ni < 4; ++ni) bv[ni] = bias[n0 + (ni << 4) + colL];
#pragma unroll
    for (int mi = 0; mi < 4; ++mi) {
#pragma unroll
      for (int j = 0; j < 4; ++j) {
        const int Rm = m0 + (mi << 4) + (g << 2) + j;
        float* rowp = outF + (size_t)Rm * 1024 + n0;
#pragma unroll
        for (int ni = 0; ni < 4; ++ni)
          rowp[(ni << 4) + colL] = acc[mi][ni][j] + bv[ni];
      }
    }
  }
}

// ---------------- windowed attention ----------------
__global__ __launch_bounds__(256) void attn_win(const __bf16* __restrict__ Qb,
                                                const __bf16* __restrict__ Kb,
                                                const __bf16* __restrict__ Vt,
                                                __bf16* __restrict__ Ob) {
  const int bh = blockIdx.x >> 5;
  const int qb = blockIdx.x & 31;
  const int b = bh >> 4, h = bh & 15;
  __shared__ __align__(16) unsigned char Qs[64 * 128];
  __shared__ __align__(16) unsigned char Ks[128 * 128];
  __shared__ __align__(16) unsigned char Vs[64 * 256];
  __shared__ __align__(16) unsigned char Ps[4 * 16 * 272];
  const int tid = threadIdx.x;
  const int lane = tid & 63;
  const int w = tid >> 6;
  const int colL = lane & 15, g = lane >> 4;
  const __bf16* Qg = Qb + (size_t)bh * 2048 * 64;
  const __bf16* Kg = Kb + (size_t)bh * 2048 * 64;
  const __bf16* Vg = Vt + (size_t)bh * 64 * 2048;
  const int t0 = qb * 64 - 64;

#pragma unroll
  for (int it = 0; it < 2; ++it) {
    int c = tid + (it << 8);
    int r = c >> 3, p = c & 7, q = p ^ (r & 7);
    GLOAD16(Qg + (size_t)(qb * 64 + r) * 64 + (q << 3), Qs + c * 16);
  }
#pragma unroll
  for (int it = 0; it < 4; ++it) {
    int c = tid + (it << 8);
    int r = c >> 3, p = c & 7, q = p ^ (r & 7);
    int tok = t0 + r;
    tok = tok < 0 ? 0 : tok;
    GLOAD16(Kg + (size_t)tok * 64 + (q << 3), Ks + c * 16);
  }
#pragma unroll
  for (int it = 0; it < 4; ++it) {
    int c = tid + (it << 8);
    int r = c >> 4, p = c & 15, q = p ^ (r & 7);
    int tk = t0 + (q << 3);
    tk = tk < 0 ? 0 : tk;
    GLOAD16(Vg + (size_t)r * 2048 + tk, Vs + c * 16);
  }
  __syncthreads();

  f32x4 sc[8] = {};
  bf16x8 qf[2];
#pragma unroll
  for (int kk = 0; kk < 2; ++kk) {
    int r = (w << 4) + colL;
    int slot = (kk << 2) + g;
    qf[kk] = *(const bf16x8*)(Qs + r * 128 + ((slot ^ (r & 7)) << 4));
  }
#pragma unroll
  for (int ni = 0; ni < 8; ++ni) {
#pragma unroll
    for (int kk = 0; kk < 2; ++kk) {
      int r = (ni << 4) + colL;
      int slot = (kk << 2) + g;
      bf16x8 kf = *(const bf16x8*)(Ks + r * 128 + ((slot ^ (r & 7)) << 4));
      sc[ni] = MFMA16(qf[kk], kf, sc[ni]);
    }
  }

  float mx[4], sm[4];
#pragma unroll
  for (int j = 0; j < 4; ++j) mx[j] = -3.0e38f;
#pragma unroll
  for (int ni = 0; ni < 8; ++ni) {
#pragma unroll
    for (int j = 0; j < 4; ++j) {
      const int qi = (w << 4) + (g << 2) + j;
      const int ki = (ni << 4) + colL;
      const bool valid = (ki > qi) && (ki <= qi + 64) && (qb > 0 || ki >= 64);
      if (!valid) sc[ni][j] = -3.0e38f;
      mx[j] = fmaxf(mx[j], sc[ni][j]);
    }
  }
#pragma unroll
  for (int j = 0; j < 4; ++j) {
    mx[j] = fmaxf(mx[j], __shfl_xor(mx[j], 1));
    mx[j] = fmaxf(mx[j], __shfl_xor(mx[j], 2));
    mx[j] = fmaxf(mx[j], __shfl_xor(mx[j], 4));
    mx[j] = fmaxf(mx[j], __shfl_xor(mx[j], 8));
    sm[j] = 0.0f;
  }
  unsigned char* ps = Ps + w * (16 * 272);
#pragma unroll
  for (int ni = 0; ni < 8; ++ni) {
#pragma unroll
    for (int j = 0; j < 4; ++j) {
      float p = __expf(sc[ni][j] - mx[j]);
      sm[j] += p;
      *(__bf16*)(ps + ((g << 2) + j) * 272 + (((ni << 4) + colL) << 1)) = (__bf16)p;
    }
  }
#pragma unroll
  for (int j = 0; j < 4; ++j) {
    sm[j] += __shfl_xor(sm[j], 1);
    sm[j] += __shfl_xor(sm[j], 2);
    sm[j] += __shfl_xor(sm[j], 4);
    sm[j] += __shfl_xor(sm[j], 8);
  }
  __syncthreads();

  f32x4 o[4] = {};
#pragma unroll
  for (int step = 0; step < 4; ++step) {
    bf16x8 pf = *(const bf16x8*)(ps + colL * 272 + (step << 6) + (g << 4));
#pragma unroll
    for (int dt = 0; dt < 4; ++dt) {
      int r = (dt << 4) + colL;
      int slot = (step << 2) + g;
      bf16x8 vf = *(const bf16x8*)(Vs + r * 256 + ((slot ^ (r & 7)) << 4));
      o[dt] = MFMA16(pf, vf, o[dt]);
    }
  }

  float rinv[4];
#pragma unroll
  for (int j = 0; j < 4; ++j) rinv[j] = 1.0f / sm[j];
#pragma unroll
  for (int dt = 0; dt < 4; ++dt) {
#pragma unroll
    for (int j = 0; j < 4; ++j) {
      const int t = qb * 64 + (w << 4) + (g << 2) + j;
      Ob[((size_t)b * 2048 + t) * 1024 + h * 64 + (dt << 4) + colL] =
          (__bf16)(o[dt][j] * rinv[j]);
    }
  }
}

extern "C" void kernel_launch(void* const* d_in, const int* in_sizes, int n_in,
                              void* d_out, int out_size, void* d_ws, size_t ws_size,
                              hipStream_t stream) {
  const float* x = (const float*)d_in[0];     // [2,2048,1024]
  const float* Wqkv = (const float*)d_in[1];  // [3072,1024]
  const float* bqkv = (const float*)d_in[2];  // [3072]
  const float* Wout = (const float*)d_in[3];  // [1024,1024]
  const float* bout = (const float*)d_in[4];  // [1024]
  float* out = (float*)d_out;                 // [2,2048,1024] fp32

  __bf16* xb = (__bf16*)d_ws;             // 4194304
  __bf16* Wqkvb = xb + 4194304;           // 3145728
  __bf16* Woutb = Wqkvb + 3145728;        // 1048576
  __bf16* Qb = Woutb + 1048576;           // 4194304 each: [B,H,2048,64]
  __bf16* Kb = Qb + 4194304;
  __bf16* Vtb = Kb + 4194304;             // [B,H,64,2048] (written transposed by gemm)
  __bf16* AOb = Vtb + 4194304;            // attn out [B,2048,1024]

  cvt3<<<4096, 256, 0, stream>>>(x, Wqkv, Wout, xb, Wqkvb, Woutb);
  // QKV: 64 m-tiles x 48 n-tiles = 3072 single-wave blocks (16m x 24n per XCD)
  gemm_sw<0, 24><<<3072, 64, 0, stream>>>(xb, Wqkvb, bqkv, nullptr, Qb, Kb, Vtb);
  attn_win<<<1024, 256, 0, stream>>>(Qb, Kb, Vtb, AOb);
  // out-proj: 64 x 16 = 1024 single-wave blocks (16m x 8n per XCD)
  gemm_sw<1, 8><<<1024, 64, 0, stream>>>(AOb, Woutb, bout, out,
                                         nullptr, nullptr, nullptr);
}

// Round 12
// 82.478 us; speedup vs baseline: 1.1691x; 1.1691x over previous
//
#include <hip/hip_runtime.h>
#include <hip/hip_bf16.h>

// LocalCausalAttention: B=2, N=2048, D=1024, H=16, DH=64, WINDOW=64
// out = ( softmax(mask(QK^T*0.125)) V ) Wout^T + bout,  QKV = x Wqkv^T + bqkv
//
// R12: 8-phase 256^2 QKV, de-SBAR0'd. R5's port had sched_barrier(0) in EVERY
//   phase before the barrier = m141's documented -40% pitfall (order-pinning).
//   This round: identical 8-phase skeleton + counted vmcnt(4)/(6) ledger +
//   setprio MFMA clusters, NO sched_barrier anywhere -- compiler schedules
//   ds_reads/waits (it emits counted lgkmcnt itself, m97).
//   + 2D per-XCD rectangle (4m x 6n per XCD, bijective for 192 blocks).
//   Everything else exactly R8 (best total 72.9): outproj 64x128 BK=64 counted,
//   cvt3, attn, V written transposed by the QKV epilogue (per-element scatter).
//
// Ledger (re-verified, loads counted individually, 2 per stage):
//   prologue: A0A1B0B1(0) + B0B1(1) + A0(1) = 14 loads, vmcnt(6) -> tile0 landed.
//   iter i (T0=2i buf0, T1=2i+1 buf1):
//    ph1 RD af0-3(T0),bf01(T0); stage A1(T1)        | MFMA q(0,0)
//    ph2 RD bf23(T0)                                | MFMA q(0,2)
//    ph3 RD af4-7(T0); stage B0(2i+2)               | MFMA q(4,2)
//    ph4 stage B1(2i+2)                             | MFMA q(4,0); vmcnt(4) -> A1(T1) landed
//    ph5 RD af0-3(T1),bf01(T1); stage A0(2i+2)      | MFMA q(0,0)
//    ph6 RD bf23(T1); stage A1(2i+2)                | MFMA q(0,2)
//    ph7 RD af4-7(T1); stage B0(2i+3)               | MFMA q(4,2)
//    ph8 stage B1(2i+3),A0(2i+3)                    | MFMA q(4,0); vmcnt(6) -> tile 2i+2 landed
//   WAR: every stage >=1 full barrier after the barrier retiring its target's last read.
//   Tail i=7: stages skipped except ph1; vmcnt(0) at ph4/ph8.

typedef __attribute__((ext_vector_type(8))) __bf16 bf16x8;
typedef __attribute__((ext_vector_type(4))) float f32x4;

#define GLOAD16(g, l)                                              \
  __builtin_amdgcn_global_load_lds(                                \
      (const __attribute__((address_space(1))) void*)(g),          \
      (__attribute__((address_space(3))) void*)(l), 16, 0, 0)

#define MFMA16(a, b, c) __builtin_amdgcn_mfma_f32_16x16x32_bf16((a), (b), (c), 0, 0, 0)

// ---------------- fused fp32 -> bf16 convert (x, Wqkv, Wout) ----------------
__global__ __launch_bounds__(256) void cvt3(const float* __restrict__ x,
                                            const float* __restrict__ wqkv,
                                            const float* __restrict__ wout,
                                            __bf16* __restrict__ xb,
                                            __bf16* __restrict__ wqkvb,
                                            __bf16* __restrict__ woutb) {
  const int blk = blockIdx.x;
  const float* src;
  __bf16* dst;
  int i;
  if (blk < 2048) {            // x: 4194304 elems
    src = x; dst = xb; i = (blk * 256 + (int)threadIdx.x) * 8;
  } else if (blk < 3584) {     // Wqkv: 3145728 elems
    src = wqkv; dst = wqkvb; i = ((blk - 2048) * 256 + (int)threadIdx.x) * 8;
  } else {                     // Wout: 1048576 elems
    src = wout; dst = woutb; i = ((blk - 3584) * 256 + (int)threadIdx.x) * 8;
  }
  f32x4 a = *(const f32x4*)(src + i);
  f32x4 b = *(const f32x4*)(src + i + 4);
  bf16x8 o;
  o[0] = (__bf16)a[0]; o[1] = (__bf16)a[1]; o[2] = (__bf16)a[2]; o[3] = (__bf16)a[3];
  o[4] = (__bf16)b[0]; o[5] = (__bf16)b[1]; o[6] = (__bf16)b[2]; o[7] = (__bf16)b[3];
  *(bf16x8*)(dst + i) = o;
}

// ---------------- 256^2 8-phase QKV GEMM (no sched_barrier) ----------------
#define BAR __builtin_amdgcn_s_barrier()

#define RD_AF(DST, ABASE, ALO)                                                     \
  _Pragma("unroll")                                                                \
  for (int a = 0; a < 4; ++a) {                                                    \
    const int r = ((ALO) + a) * 16 + colL;                                         \
    _Pragma("unroll")                                                              \
    for (int kk = 0; kk < 2; ++kk)                                                 \
      DST[a][kk] = *(const bf16x8*)((ABASE) + r * 128 +                            \
                                    ((((kk << 2) + g) ^ (r & 7)) << 4));           \
  }

#define RD_BF(DST, BBASE, NLO)                                                     \
  _Pragma("unroll")                                                                \
  for (int nb = 0; nb < 2; ++nb) {                                                 \
    const int r = ((wn & 1) << 6) + ((NLO) + nb) * 16 + colL;                      \
    _Pragma("unroll")                                                              \
    for (int kk = 0; kk < 2; ++kk)                                                 \
      DST[nb][kk] = *(const bf16x8*)((BBASE) + r * 128 +                           \
                                     ((((kk << 2) + g) ^ (r & 7)) << 4));          \
  }

#define QUADM(ALO, NLO, AF, BF)                                                    \
  __builtin_amdgcn_s_setprio(1);                                                   \
  _Pragma("unroll")                                                                \
  for (int a = 0; a < 4; ++a)                                                      \
    _Pragma("unroll")                                                              \
    for (int nb = 0; nb < 2; ++nb) {                                               \
      acc[(ALO) + a][(NLO) + nb] =                                                 \
          MFMA16(AF[a][0], BF[nb][0], acc[(ALO) + a][(NLO) + nb]);                 \
      acc[(ALO) + a][(NLO) + nb] =                                                 \
          MFMA16(AF[a][1], BF[nb][1], acc[(ALO) + a][(NLO) + nb]);                 \
    }                                                                              \
  __builtin_amdgcn_s_setprio(0);

__global__ __launch_bounds__(512, 2) void gemm256_qkv(
    const __bf16* __restrict__ A, const __bf16* __restrict__ Bw,
    const float* __restrict__ bias,
    __bf16* __restrict__ qo, __bf16* __restrict__ ko, __bf16* __restrict__ vt) {
  constexpr int K = 1024;
  __shared__ __align__(16) unsigned char AsBuf[2][32768];  // [buf][half0|half1]
  __shared__ __align__(16) unsigned char BsBuf[2][32768];
  const int tid = threadIdx.x;
  const int lane = tid & 63;
  const int wid = tid >> 6;               // 0..7
  const int wm = wid >> 2, wn = wid & 3;  // 2M x 4N
  const int colL = lane & 15, g = lane >> 4;

  // 2D per-XCD rectangle: xcd owns 4m x 6n 256^2 tiles (bijective, 192 blocks)
  const int xcd = (int)blockIdx.x & 7;
  const int i0 = (int)blockIdx.x >> 3;       // [0,24)
  const int mR = (xcd >> 1) * 4 + i0 / 6;    // [0,16)
  const int nR = (xcd & 1) * 6 + i0 % 6;     // [0,12)
  const int m0 = mR * 256, n0 = nR * 256;

  const __bf16* Ap0 = A + (size_t)m0 * K;
  const __bf16* Ap1 = A + (size_t)(m0 + 128) * K;
  const __bf16* Bp0 = Bw + (size_t)n0 * K;
  const __bf16* Bp1 = Bw + (size_t)(n0 + 128) * K;

  // one half-tile (128 rows x 64 cols = 16KB): linear LDS dest, inv-swizzled src
  auto stage = [&](const __bf16* src, unsigned char* lds, int k0) {
#pragma unroll
    for (int it = 0; it < 2; ++it) {
      int c = tid + (it << 9);
      int row = c >> 3, pp = c & 7;
      int q = pp ^ (row & 7);
      GLOAD16(src + (size_t)row * K + k0 + (q << 3), lds + c * 16);
    }
  };

  f32x4 acc[8][4] = {};

  const unsigned char* A0b = AsBuf[0] + (wm << 14);
  const unsigned char* A1b = AsBuf[1] + (wm << 14);
  const unsigned char* B0b = BsBuf[0] + ((wn >> 1) << 14);
  const unsigned char* B1b = BsBuf[1] + ((wn >> 1) << 14);

  // prologue: tile0 {A0,A1,B0,B1}, tile1 {B0,B1,A0}; A1(1) staged at iter0-ph1
  stage(Ap0, AsBuf[0], 0);
  stage(Ap1, AsBuf[0] + 16384, 0);
  stage(Bp0, BsBuf[0], 0);
  stage(Bp1, BsBuf[0] + 16384, 0);
  stage(Bp0, BsBuf[1], 64);
  stage(Bp1, BsBuf[1] + 16384, 64);
  stage(Ap0, AsBuf[1], 64);
  asm volatile("s_waitcnt vmcnt(6)" ::: "memory");  // tile0 landed; 6 loads in flight
  BAR;

  for (int i = 0; i < 8; ++i) {
    const bool lst = (i == 7);
    const int kc1 = (2 * i + 1) << 6;
    const int kc2 = (2 * i + 2) << 6;
    const int kc3 = (2 * i + 3) << 6;
    bf16x8 afA[4][2], afB[4][2], bfA[2][2], bfB[2][2];

    // ph1
    RD_AF(afA, A0b, 0);
    RD_BF(bfA, B0b, 0);
    stage(Ap1, AsBuf[1] + 16384, kc1);
    BAR;
    QUADM(0, 0, afA, bfA);
    BAR;

    // ph2
    RD_BF(bfB, B0b, 2);
    BAR;
    QUADM(0, 2, afA, bfB);
    BAR;

    // ph3
    RD_AF(afB, A0b, 4);
    if (!lst) stage(Bp0, BsBuf[0], kc2);
    BAR;
    QUADM(4, 2, afB, bfB);
    BAR;

    // ph4
    if (!lst) stage(Bp1, BsBuf[0] + 16384, kc2);
    BAR;
    QUADM(4, 0, afB, bfA);
    if (!lst) asm volatile("s_waitcnt vmcnt(4)" ::: "memory");
    else      asm volatile("s_waitcnt vmcnt(0)" ::: "memory");
    BAR;

    // ph5
    RD_AF(afA, A1b, 0);
    RD_BF(bfA, B1b, 0);
    if (!lst) stage(Ap0, AsBuf[0], kc2);
    BAR;
    QUADM(0, 0, afA, bfA);
    BAR;

    // ph6
    RD_BF(bfB, B1b, 2);
    if (!lst) stage(Ap1, AsBuf[0] + 16384, kc2);
    BAR;
    QUADM(0, 2, afA, bfB);
    BAR;

    // ph7
    RD_AF(afB, A1b, 4);
    if (!lst) stage(Bp0, BsBuf[1], kc3);
    BAR;
    QUADM(4, 2, afB, bfB);
    BAR;

    // ph8
    if (!lst) { stage(Bp1, BsBuf[1] + 16384, kc3); stage(Ap0, AsBuf[1], kc3); }
    BAR;
    QUADM(4, 0, afB, bfA);
    if (!lst) asm volatile("s_waitcnt vmcnt(6)" ::: "memory");
    else      asm volatile("s_waitcnt vmcnt(0)" ::: "memory");
    BAR;
  }

  // epilogue: C/D layout col=lane&15, row=(lane>>4)*4+reg (m89-verified).
  // Wave's 64-col range = one of Q/K/V, one head.
  const int Cn0 = n0 + wn * 64;
  const int sx = Cn0 >> 10, h = (Cn0 >> 6) & 15;
  float bv[4];
#pragma unroll
  for (int ni = 0; ni < 4; ++ni) bv[ni] = bias[Cn0 + (ni << 4) + colL];
  if (sx == 2) {
    // V: per-element transposed scatter into Vt[bh][d][2048] (L2 absorbs)
#pragma unroll
    for (int mi = 0; mi < 8; ++mi) {
#pragma unroll
      for (int j = 0; j < 4; ++j) {
        const int Rm = m0 + wm * 128 + mi * 16 + (g << 2) + j;
        const int bb = Rm >> 11, tt = Rm & 2047;
#pragma unroll
        for (int ni = 0; ni < 4; ++ni) {
          const int d = (ni << 4) + colL;
          vt[(((size_t)bb * 16 + h) * 64 + d) * 2048 + tt] =
              (__bf16)(acc[mi][ni][j] + bv[ni]);
        }
      }
    }
  } else {
    __bf16* dst = (sx == 0) ? qo : ko;
    const float mul = (sx == 0) ? 0.125f : 1.0f;  // fold SCALE into Q (exact pow2)
#pragma unroll
    for (int mi = 0; mi < 8; ++mi) {
#pragma unroll
      for (int j = 0; j < 4; ++j) {
        const int Rm = m0 + wm * 128 + mi * 16 + (g << 2) + j;
        const int bb = Rm >> 11, tt = Rm & 2047;
        __bf16* rowp = dst + (((size_t)bb * 16 + h) * 2048 + tt) * 64;
#pragma unroll
        for (int ni = 0; ni < 4; ++ni)  // 4 x 32B bursts -> full 128B line
          rowp[(ni << 4) + colL] = (__bf16)((acc[mi][ni][j] + bv[ni]) * mul);
      }
    }
  }
}

// ---------------- 64x128 BK=64 counted-vmcnt dbuf GEMM (out-proj, R8-verified) ----
__global__ __launch_bounds__(128) void gemm_out(
    const __bf16* __restrict__ A, const __bf16* __restrict__ Bw,
    const float* __restrict__ bias, int N,
    float* __restrict__ outF, int nbn, int chunk) {
  constexpr int K = 1024;
  constexpr int ASZ = 8192;
  constexpr int BUF = ASZ + 16384;
  __shared__ __align__(16) unsigned char Ls[2 * BUF];
  const int tid = threadIdx.x;
  const int lane = tid & 63;
  const int wc = tid >> 6;
  const int colL = lane & 15, g = lane >> 4;

  int s = (int)blockIdx.x;
  s = (s & 7) * chunk + (s >> 3);
  const int m0 = (s / nbn) * 64, n0 = (s % nbn) * 128;

  const __bf16* Ap = A + (size_t)m0 * K;
  const __bf16* Bp = Bw + (size_t)n0 * K;

  auto stageA = [&](unsigned char* lds, int k0) {
#pragma unroll
    for (int it = 0; it < 4; ++it) {
      int c = tid + it * 128;
      int row = c >> 3, p = c & 7, q = p ^ (row & 7);
      GLOAD16(Ap + (size_t)row * K + k0 + (q << 3), lds + c * 16);
    }
  };
  auto stageB = [&](unsigned char* lds, int k0) {
#pragma unroll
    for (int it = 0; it < 8; ++it) {
      int c = tid + it * 128;
      int row = c >> 3, p = c & 7, q = p ^ (row & 7);
      GLOAD16(Bp + (size_t)row * K + k0 + (q << 3), lds + c * 16);
    }
  };

  f32x4 acc[4][4] = {};

  stageA(Ls, 0);
  stageB(Ls + ASZ, 0);
  stageA(Ls + BUF, 64);
  stageB(Ls + BUF + ASZ, 64);
  asm volatile("s_waitcnt vmcnt(12)" ::: "memory");
  __builtin_amdgcn_s_barrier();

  constexpr int nT = 16;
  for (int t = 0; t < nT; ++t) {
    const unsigned char* Ab = Ls + (t & 1) * BUF;
    const unsigned char* Bb = Ab + ASZ;
    bf16x8 af[4][2], bf[4][2];
#pragma unroll
    for (int mi = 0; mi < 4; ++mi) {
      const int r = (mi << 4) + colL;
#pragma unroll
      for (int kk = 0; kk < 2; ++kk)
        af[mi][kk] = *(const bf16x8*)(Ab + r * 128 + ((((kk << 2) + g) ^ (r & 7)) << 4));
    }
#pragma unroll
    for (int ni = 0; ni < 4; ++ni) {
      const int r = (wc << 6) + (ni << 4) + colL;
#pragma unroll
      for (int kk = 0; kk < 2; ++kk)
        bf[ni][kk] = *(const bf16x8*)(Bb + r * 128 + ((((kk << 2) + g) ^ (r & 7)) << 4));
    }
#pragma unroll
    for (int mi = 0; mi < 4; ++mi)
#pragma unroll
      for (int ni = 0; ni < 4; ++ni) {
        acc[mi][ni] = MFMA16(af[mi][0], bf[ni][0], acc[mi][ni]);
        acc[mi][ni] = MFMA16(af[mi][1], bf[ni][1], acc[mi][ni]);
      }
    asm volatile("s_waitcnt lgkmcnt(0)" ::: "memory");
    __builtin_amdgcn_s_barrier();
    if (t < nT - 2) {
      const int kn = (t + 2) << 6;
      unsigned char* dst = Ls + (t & 1) * BUF;
      stageA(dst, kn);
      stageB(dst + ASZ, kn);
      asm volatile("s_waitcnt vmcnt(12)" ::: "memory");
    } else {
      asm volatile("s_waitcnt vmcnt(0)" ::: "memory");
    }
    __builtin_amdgcn_s_barrier();
  }

  float bv[4];
#pragma unroll
  for (int ni = 0; ni < 4; ++ni) bv[ni] = bias[n0 + (wc << 6) + (ni << 4) + colL];
#pragma unroll
  for (int mi = 0; mi < 4; ++mi) {
#pragma unroll
    for (int j = 0; j < 4; ++j) {
      const int Rm = m0 + (mi << 4) + (g << 2) + j;
      float* rowp = outF + (size_t)Rm * N + n0 + (wc << 6);
#pragma unroll
      for (int ni = 0; ni < 4; ++ni)
        rowp[(ni << 4) + colL] = acc[mi][ni][j] + bv[ni];
    }
  }
}

// ---------------- windowed attention ----------------
__global__ __launch_bounds__(256) void attn_win(const __bf16* __restrict__ Qb,
                                                const __bf16* __restrict__ Kb,
                                                const __bf16* __restrict__ Vt,
                                                __bf16* __restrict__ Ob) {
  const int bh = blockIdx.x >> 5;
  const int qb = blockIdx.x & 31;
  const int b = bh >> 4, h = bh & 15;
  __shared__ __align__(16) unsigned char Qs[64 * 128];
  __shared__ __align__(16) unsigned char Ks[128 * 128];
  __shared__ __align__(16) unsigned char Vs[64 * 256];
  __shared__ __align__(16) unsigned char Ps[4 * 16 * 272];
  const int tid = threadIdx.x;
  const int lane = tid & 63;
  const int w = tid >> 6;
  const int colL = lane & 15, g = lane >> 4;
  const __bf16* Qg = Qb + (size_t)bh * 2048 * 64;
  const __bf16* Kg = Kb + (size_t)bh * 2048 * 64;
  const __bf16* Vg = Vt + (size_t)bh * 64 * 2048;
  const int t0 = qb * 64 - 64;

#pragma unroll
  for (int it = 0; it < 2; ++it) {
    int c = tid + (it << 8);
    int r = c >> 3, p = c & 7, q = p ^ (r & 7);
    GLOAD16(Qg + (size_t)(qb * 64 + r) * 64 + (q << 3), Qs + c * 16);
  }
#pragma unroll
  for (int it = 0; it < 4; ++it) {
    int c = tid + (it << 8);
    int r = c >> 3, p = c & 7, q = p ^ (r & 7);
    int tok = t0 + r;
    tok = tok < 0 ? 0 : tok;
    GLOAD16(Kg + (size_t)tok * 64 + (q << 3), Ks + c * 16);
  }
#pragma unroll
  for (int it = 0; it < 4; ++it) {
    int c = tid + (it << 8);
    int r = c >> 4, p = c & 15, q = p ^ (r & 7);
    int tk = t0 + (q << 3);
    tk = tk < 0 ? 0 : tk;
    GLOAD16(Vg + (size_t)r * 2048 + tk, Vs + c * 16);
  }
  __syncthreads();

  f32x4 sc[8] = {};
  bf16x8 qf[2];
#pragma unroll
  for (int kk = 0; kk < 2; ++kk) {
    int r = (w << 4) + colL;
    int slot = (kk << 2) + g;
    qf[kk] = *(const bf16x8*)(Qs + r * 128 + ((slot ^ (r & 7)) << 4));
  }
#pragma unroll
  for (int ni = 0; ni < 8; ++ni) {
#pragma unroll
    for (int kk = 0; kk < 2; ++kk) {
      int r = (ni << 4) + colL;
      int slot = (kk << 2) + g;
      bf16x8 kf = *(const bf16x8*)(Ks + r * 128 + ((slot ^ (r & 7)) << 4));
      sc[ni] = MFMA16(qf[kk], kf, sc[ni]);
    }
  }

  float mx[4], sm[4];
#pragma unroll
  for (int j = 0; j < 4; ++j) mx[j] = -3.0e38f;
#pragma unroll
  for (int ni = 0; ni < 8; ++ni) {
#pragma unroll
    for (int j = 0; j < 4; ++j) {
      const int qi = (w << 4) + (g << 2) + j;
      const int ki = (ni << 4) + colL;
      const bool valid = (ki > qi) && (ki <= qi + 64) && (qb > 0 || ki >= 64);
      if (!valid) sc[ni][j] = -3.0e38f;
      mx[j] = fmaxf(mx[j], sc[ni][j]);
    }
  }
#pragma unroll
  for (int j = 0; j < 4; ++j) {
    mx[j] = fmaxf(mx[j], __shfl_xor(mx[j], 1));
    mx[j] = fmaxf(mx[j], __shfl_xor(mx[j], 2));
    mx[j] = fmaxf(mx[j], __shfl_xor(mx[j], 4));
    mx[j] = fmaxf(mx[j], __shfl_xor(mx[j], 8));
    sm[j] = 0.0f;
  }
  unsigned char* ps = Ps + w * (16 * 272);
#pragma unroll
  for (int ni = 0; ni < 8; ++ni) {
#pragma unroll
    for (int j = 0; j < 4; ++j) {
      float p = __expf(sc[ni][j] - mx[j]);
      sm[j] += p;
      *(__bf16*)(ps + ((g << 2) + j) * 272 + (((ni << 4) + colL) << 1)) = (__bf16)p;
    }
  }
#pragma unroll
  for (int j = 0; j < 4; ++j) {
    sm[j] += __shfl_xor(sm[j], 1);
    sm[j] += __shfl_xor(sm[j], 2);
    sm[j] += __shfl_xor(sm[j], 4);
    sm[j] += __shfl_xor(sm[j], 8);
  }
  __syncthreads();

  f32x4 o[4] = {};
#pragma unroll
  for (int step = 0; step < 4; ++step) {
    bf16x8 pf = *(const bf16x8*)(ps + colL * 272 + (step << 6) + (g << 4));
#pragma unroll
    for (int dt = 0; dt < 4; ++dt) {
      int r = (dt << 4) + colL;
      int slot = (step << 2) + g;
      bf16x8 vf = *(const bf16x8*)(Vs + r * 256 + ((slot ^ (r & 7)) << 4));
      o[dt] = MFMA16(pf, vf, o[dt]);
    }
  }

  float rinv[4];
#pragma unroll
  for (int j = 0; j < 4; ++j) rinv[j] = 1.0f / sm[j];
#pragma unroll
  for (int dt = 0; dt < 4; ++dt) {
#pragma unroll
    for (int j = 0; j < 4; ++j) {
      const int t = qb * 64 + (w << 4) + (g << 2) + j;
      Ob[((size_t)b * 2048 + t) * 1024 + h * 64 + (dt << 4) + colL] =
          (__bf16)(o[dt][j] * rinv[j]);
    }
  }
}

extern "C" void kernel_launch(void* const* d_in, const int* in_sizes, int n_in,
                              void* d_out, int out_size, void* d_ws, size_t ws_size,
                              hipStream_t stream) {
  const float* x = (const float*)d_in[0];     // [2,2048,1024]
  const float* Wqkv = (const float*)d_in[1];  // [3072,1024]
  const float* bqkv = (const float*)d_in[2];  // [3072]
  const float* Wout = (const float*)d_in[3];  // [1024,1024]
  const float* bout = (const float*)d_in[4];  // [1024]
  float* out = (float*)d_out;                 // [2,2048,1024] fp32

  __bf16* xb = (__bf16*)d_ws;             // 4194304
  __bf16* Wqkvb = xb + 4194304;           // 3145728
  __bf16* Woutb = Wqkvb + 3145728;        // 1048576
  __bf16* Qb = Woutb + 1048576;           // 4194304 each: [B,H,2048,64]
  __bf16* Kb = Qb + 4194304;
  __bf16* Vtb = Kb + 4194304;             // [B,H,64,2048] (written transposed by gemm)
  __bf16* AOb = Vtb + 4194304;            // attn out [B,2048,1024]

  cvt3<<<4096, 256, 0, stream>>>(x, Wqkv, Wout, xb, Wqkvb, Woutb);
  gemm256_qkv<<<192, 512, 0, stream>>>(xb, Wqkvb, bqkv, Qb, Kb, Vtb);
  attn_win<<<1024, 256, 0, stream>>>(Qb, Kb, Vtb, AOb);
  gemm_out<<<512, 128, 0, stream>>>(AOb, Woutb, bout, 1024, out, 8, 64);
}

// Round 13
// 77.845 us; speedup vs baseline: 1.2387x; 1.0595x over previous
//
#include <hip/hip_runtime.h>
#include <hip/hip_bf16.h>

// LocalCausalAttention: B=2, N=2048, D=1024, H=16, DH=64, WINDOW=64
// out = ( softmax(mask(QK^T*0.125)) V ) Wout^T + bout,  QKV = x Wqkv^T + bqkv
//
// R13: isolation round. R6's champion QKV loop VERBATIM (128^2, BK=32, 2-buffer
//   counted-vmcnt, stage2-recomputed addressing, 1D 96/XCD chunk) with the
//   V-LDS-transpose epilogue moved INTO the 32768B staging LDS (aliased after
//   the K-loop retires it) via XOR-swizzled scratch -- no extra 4KB, no padding.
//   Hypothesis: R9/R10's QKV regression (46.7 -> 51.6) was the LDS 32768->36864
//   bump (occupancy 26.6 -> 15.2), not the epilogue content.
//   wreg layout: u32 @ wid*8192 + d*128 + ((tt*2) ^ ((d&7)<<4)); read with the
//   same XOR at tt=(lane&31)*2. Writes <=4-way on 32 instrs (negligible),
//   reads conflict-free, per-wave disjoint regions (no barrier needed).
//   out-proj / cvt3 / attn = R8 exactly.

typedef __attribute__((ext_vector_type(8))) __bf16 bf16x8;
typedef __attribute__((ext_vector_type(4))) float f32x4;

#define GLOAD16(g, l)                                              \
  __builtin_amdgcn_global_load_lds(                                \
      (const __attribute__((address_space(1))) void*)(g),          \
      (__attribute__((address_space(3))) void*)(l), 16, 0, 0)

#define MFMA16(a, b, c) __builtin_amdgcn_mfma_f32_16x16x32_bf16((a), (b), (c), 0, 0, 0)

// ---------------- fused fp32 -> bf16 convert (x, Wqkv, Wout) ----------------
__global__ __launch_bounds__(256) void cvt3(const float* __restrict__ x,
                                            const float* __restrict__ wqkv,
                                            const float* __restrict__ wout,
                                            __bf16* __restrict__ xb,
                                            __bf16* __restrict__ wqkvb,
                                            __bf16* __restrict__ woutb) {
  const int blk = blockIdx.x;
  const float* src;
  __bf16* dst;
  int i;
  if (blk < 2048) {            // x: 4194304 elems
    src = x; dst = xb; i = (blk * 256 + (int)threadIdx.x) * 8;
  } else if (blk < 3584) {     // Wqkv: 3145728 elems
    src = wqkv; dst = wqkvb; i = ((blk - 2048) * 256 + (int)threadIdx.x) * 8;
  } else {                     // Wout: 1048576 elems
    src = wout; dst = woutb; i = ((blk - 3584) * 256 + (int)threadIdx.x) * 8;
  }
  f32x4 a = *(const f32x4*)(src + i);
  f32x4 b = *(const f32x4*)(src + i + 4);
  bf16x8 o;
  o[0] = (__bf16)a[0]; o[1] = (__bf16)a[1]; o[2] = (__bf16)a[2]; o[3] = (__bf16)a[3];
  o[4] = (__bf16)b[0]; o[5] = (__bf16)b[1]; o[6] = (__bf16)b[2]; o[7] = (__bf16)b[3];
  *(bf16x8*)(dst + i) = o;
}

// ---------------- 128^2 BK=32 counted-vmcnt QKV GEMM (R6 loop verbatim) ----------------
// C[m,n] = sum_k A[m,k]*Wqkv[n,k] + bqkv[n]; M=4096,N=3072,K=1024 fixed.
// 4 waves (2x2), per-wave 64x64. LDS exactly 32768: 2x16KB bufs, epilogue aliases them.
__global__ __launch_bounds__(256) void gemm_qkv(
    const __bf16* __restrict__ A, const __bf16* __restrict__ Bw,
    const float* __restrict__ bias,
    __bf16* __restrict__ qo, __bf16* __restrict__ ko, __bf16* __restrict__ vt) {
  constexpr int K = 1024;
  __shared__ __align__(16) unsigned char Ls[32768];
  const int tid = threadIdx.x;
  const int lane = tid & 63;
  const int wid = tid >> 6;
  const int wr = wid >> 1, wc = wid & 1;
  const int colL = lane & 15, g = lane >> 4;

  // 1D XCD chunking (R6-exact): 768 blocks = 96/XCD, n fastest within chunk
  int s = (int)blockIdx.x;
  s = (s & 7) * 96 + (s >> 3);
  const int m0 = (s / 24) * 128, n0 = (s % 24) * 128;

  const __bf16* Ap = A + (size_t)m0 * K;
  const __bf16* Bp = Bw + (size_t)n0 * K;

  // stage one matrix half-step (128 rows x 32 cols = 8KB), paired-row layout:
  // linear LDS dest c*16; line L=c>>3, s6=c&7; u=s6^(L&7) -> row=2L+(u>>2), p=u&3.
  auto stage2 = [&](const __bf16* src, unsigned char* lds, int k0) {
#pragma unroll
    for (int it = 0; it < 2; ++it) {
      int c = tid + (it << 8);       // 0..511
      int L = c >> 3, s6 = c & 7;
      int u = s6 ^ (L & 7);
      int row = (L << 1) | (u >> 2), p = u & 3;
      GLOAD16(src + (size_t)row * K + k0 + (p << 3), lds + c * 16);
    }
  };

  f32x4 acc[4][4] = {};

  // prologue: tiles 0,1 into bufs 0,1
  stage2(Ap, Ls, 0);
  stage2(Bp, Ls + 8192, 0);
  stage2(Ap, Ls + 16384, 32);
  stage2(Bp, Ls + 24576, 32);
  asm volatile("s_waitcnt vmcnt(4)" ::: "memory");  // tile0 landed; tile1 in flight
  __builtin_amdgcn_s_barrier();

  const int nT = K >> 5;  // 32 steps
  for (int t = 0; t < nT; ++t) {
    const unsigned char* Ab = Ls + (t & 1) * 16384;
    const unsigned char* Bb = Ab + 8192;
    bf16x8 af[4], bf[4];
#pragma unroll
    for (int mi = 0; mi < 4; ++mi) {
      const int r = (wr << 6) + (mi << 4) + colL;
      af[mi] = *(const bf16x8*)(Ab + (r >> 1) * 128 +
                                (((((r & 1) << 2) | g) ^ ((r >> 1) & 7)) << 4));
    }
#pragma unroll
    for (int ni = 0; ni < 4; ++ni) {
      const int r = (wc << 6) + (ni << 4) + colL;
      bf[ni] = *(const bf16x8*)(Bb + (r >> 1) * 128 +
                                (((((r & 1) << 2) | g) ^ ((r >> 1) & 7)) << 4));
    }
#pragma unroll
    for (int mi = 0; mi < 4; ++mi)
#pragma unroll
      for (int ni = 0; ni < 4; ++ni)
        acc[mi][ni] = MFMA16(af[mi], bf[ni], acc[mi][ni]);
    // all this wave's ds_reads executed before anyone may DMA-overwrite buf[cur]
    asm volatile("s_waitcnt lgkmcnt(0)" ::: "memory");
    __builtin_amdgcn_s_barrier();
    if (t < nT - 2) {
      const int kn = (t + 2) << 5;
      unsigned char* dst = Ls + (t & 1) * 16384;  // overwrite just-retired buffer
      stage2(Ap, dst, kn);
      stage2(Bp, dst + 8192, kn);
      // in flight: tile t+1 (4) + tile t+2 (4); retire oldest 4 -> t+1 validated
      asm volatile("s_waitcnt vmcnt(4)" ::: "memory");
    } else {
      asm volatile("s_waitcnt vmcnt(0)" ::: "memory");  // tail: drain last tile
    }
    __builtin_amdgcn_s_barrier();
  }

  // epilogue: C/D layout col=lane&15, row=(lane>>4)*4+reg (m89-verified)
  const int Cn0 = n0 + (wc << 6);              // wave's 64-col half: sx/h const
  const int sx = Cn0 >> 10, h = (Cn0 >> 6) & 15;
  float bv[4];
#pragma unroll
  for (int ni = 0; ni < 4; ++ni) bv[ni] = bias[Cn0 + (ni << 4) + colL];
  const int b = m0 >> 11;
  if (sx == 2) {
    // ---- V: transpose via ALIASED swizzled LDS scratch (8KB/wave in Ls) ----
    // (K-loop fully retired: last iteration ends with vmcnt(0)+barrier.)
    unsigned char* wreg = Ls + wid * 8192;     // per-wave [64 d][64 tt] u16, XOR-swz
#pragma unroll
    for (int mi = 0; mi < 4; ++mi)
#pragma unroll
      for (int ni = 0; ni < 4; ++ni)
#pragma unroll
        for (int jp = 0; jp < 2; ++jp) {
          const int tt = (mi << 4) + (g << 2) + (jp << 1);
          const int d = (ni << 4) + colL;
          unsigned short u0 = __builtin_bit_cast(
              unsigned short, (__bf16)(acc[mi][ni][jp * 2] + bv[ni]));
          unsigned short u1 = __builtin_bit_cast(
              unsigned short, (__bf16)(acc[mi][ni][jp * 2 + 1] + bv[ni]));
          *(unsigned int*)(wreg + (d << 7) + (((tt << 1) ^ ((d & 7) << 4)))) =
              (unsigned int)u0 | ((unsigned int)u1 << 16);
        }
    asm volatile("s_waitcnt lgkmcnt(0)" ::: "memory");
    const size_t vbase = (size_t)(b * 16 + h) * 64 * 2048;
    const int tg0 = (m0 & 2047) + (wr << 6);
#pragma unroll
    for (int i2 = 0; i2 < 32; ++i2) {
      const int d = (i2 << 1) + (lane >> 5);
      const int toff = (lane & 31) << 1;
      unsigned int v = *(unsigned int*)(wreg + (d << 7) +
                                        ((((lane & 31) << 2)) ^ ((d & 7) << 4)));
      *(unsigned int*)((unsigned short*)vt + vbase + (size_t)d * 2048 + tg0 + toff) = v;
    }
  } else {
    __bf16* dst = (sx == 0) ? qo : ko;
    const float mul = (sx == 0) ? 0.125f : 1.0f;  // fold SCALE into Q (exact pow2)
#pragma unroll
    for (int mi = 0; mi < 4; ++mi) {
#pragma unroll
      for (int j = 0; j < 4; ++j) {
        const int Rm = m0 + (wr << 6) + (mi << 4) + (g << 2) + j;
        const int tt = Rm & 2047;
        __bf16* rowp = dst + (((size_t)b * 16 + h) * 2048 + tt) * 64;
#pragma unroll
        for (int ni = 0; ni < 4; ++ni)  // 4 x 32B bursts -> full 128B line
          rowp[(ni << 4) + colL] = (__bf16)((acc[mi][ni][j] + bv[ni]) * mul);
      }
    }
  }
}

// ---------------- 64x128 BK=64 counted-vmcnt dbuf GEMM (out-proj, R8-verified) ----------------
__global__ __launch_bounds__(128) void gemm_out(
    const __bf16* __restrict__ A, const __bf16* __restrict__ Bw,
    const float* __restrict__ bias, int N,
    float* __restrict__ outF, int nbn, int chunk) {
  constexpr int K = 1024;
  constexpr int ASZ = 8192;          // A half: 64 rows x 128B
  constexpr int BUF = ASZ + 16384;   // + B half: 128 rows x 128B
  __shared__ __align__(16) unsigned char Ls[2 * BUF];
  const int tid = threadIdx.x;
  const int lane = tid & 63;
  const int wc = tid >> 6;
  const int colL = lane & 15, g = lane >> 4;

  int s = (int)blockIdx.x;
  s = (s & 7) * chunk + (s >> 3);
  const int m0 = (s / nbn) * 64, n0 = (s % nbn) * 128;

  const __bf16* Ap = A + (size_t)m0 * K;
  const __bf16* Bp = Bw + (size_t)n0 * K;

  auto stageA = [&](unsigned char* lds, int k0) {
#pragma unroll
    for (int it = 0; it < 4; ++it) {
      int c = tid + it * 128;
      int row = c >> 3, p = c & 7, q = p ^ (row & 7);
      GLOAD16(Ap + (size_t)row * K + k0 + (q << 3), lds + c * 16);
    }
  };
  auto stageB = [&](unsigned char* lds, int k0) {
#pragma unroll
    for (int it = 0; it < 8; ++it) {
      int c = tid + it * 128;
      int row = c >> 3, p = c & 7, q = p ^ (row & 7);
      GLOAD16(Bp + (size_t)row * K + k0 + (q << 3), lds + c * 16);
    }
  };

  f32x4 acc[4][4] = {};

  stageA(Ls, 0);
  stageB(Ls + ASZ, 0);
  stageA(Ls + BUF, 64);
  stageB(Ls + BUF + ASZ, 64);
  asm volatile("s_waitcnt vmcnt(12)" ::: "memory");
  __builtin_amdgcn_s_barrier();

  constexpr int nT = 16;
  for (int t = 0; t < nT; ++t) {
    const unsigned char* Ab = Ls + (t & 1) * BUF;
    const unsigned char* Bb = Ab + ASZ;
    bf16x8 af[4][2], bf[4][2];
#pragma unroll
    for (int mi = 0; mi < 4; ++mi) {
      const int r = (mi << 4) + colL;
#pragma unroll
      for (int kk = 0; kk < 2; ++kk)
        af[mi][kk] = *(const bf16x8*)(Ab + r * 128 + ((((kk << 2) + g) ^ (r & 7)) << 4));
    }
#pragma unroll
    for (int ni = 0; ni < 4; ++ni) {
      const int r = (wc << 6) + (ni << 4) + colL;
#pragma unroll
      for (int kk = 0; kk < 2; ++kk)
        bf[ni][kk] = *(const bf16x8*)(Bb + r * 128 + ((((kk << 2) + g) ^ (r & 7)) << 4));
    }
#pragma unroll
    for (int mi = 0; mi < 4; ++mi)
#pragma unroll
      for (int ni = 0; ni < 4; ++ni) {
        acc[mi][ni] = MFMA16(af[mi][0], bf[ni][0], acc[mi][ni]);
        acc[mi][ni] = MFMA16(af[mi][1], bf[ni][1], acc[mi][ni]);
      }
    asm volatile("s_waitcnt lgkmcnt(0)" ::: "memory");
    __builtin_amdgcn_s_barrier();
    if (t < nT - 2) {
      const int kn = (t + 2) << 6;
      unsigned char* dst = Ls + (t & 1) * BUF;
      stageA(dst, kn);
      stageB(dst + ASZ, kn);
      asm volatile("s_waitcnt vmcnt(12)" ::: "memory");
    } else {
      asm volatile("s_waitcnt vmcnt(0)" ::: "memory");
    }
    __builtin_amdgcn_s_barrier();
  }

  float bv[4];
#pragma unroll
  for (int ni = 0; ni < 4; ++ni) bv[ni] = bias[n0 + (wc << 6) + (ni << 4) + colL];
#pragma unroll
  for (int mi = 0; mi < 4; ++mi) {
#pragma unroll
    for (int j = 0; j < 4; ++j) {
      const int Rm = m0 + (mi << 4) + (g << 2) + j;
      float* rowp = outF + (size_t)Rm * N + n0 + (wc << 6);
#pragma unroll
      for (int ni = 0; ni < 4; ++ni)
        rowp[(ni << 4) + colL] = acc[mi][ni][j] + bv[ni];
    }
  }
}

// ---------------- windowed attention ----------------
__global__ __launch_bounds__(256) void attn_win(const __bf16* __restrict__ Qb,
                                                const __bf16* __restrict__ Kb,
                                                const __bf16* __restrict__ Vt,
                                                __bf16* __restrict__ Ob) {
  const int bh = blockIdx.x >> 5;
  const int qb = blockIdx.x & 31;
  const int b = bh >> 4, h = bh & 15;
  __shared__ __align__(16) unsigned char Qs[64 * 128];
  __shared__ __align__(16) unsigned char Ks[128 * 128];
  __shared__ __align__(16) unsigned char Vs[64 * 256];
  __shared__ __align__(16) unsigned char Ps[4 * 16 * 272];
  const int tid = threadIdx.x;
  const int lane = tid & 63;
  const int w = tid >> 6;
  const int colL = lane & 15, g = lane >> 4;
  const __bf16* Qg = Qb + (size_t)bh * 2048 * 64;
  const __bf16* Kg = Kb + (size_t)bh * 2048 * 64;
  const __bf16* Vg = Vt + (size_t)bh * 64 * 2048;
  const int t0 = qb * 64 - 64;

#pragma unroll
  for (int it = 0; it < 2; ++it) {
    int c = tid + (it << 8);
    int r = c >> 3, p = c & 7, q = p ^ (r & 7);
    GLOAD16(Qg + (size_t)(qb * 64 + r) * 64 + (q << 3), Qs + c * 16);
  }
#pragma unroll
  for (int it = 0; it < 4; ++it) {
    int c = tid + (it << 8);
    int r = c >> 3, p = c & 7, q = p ^ (r & 7);
    int tok = t0 + r;
    tok = tok < 0 ? 0 : tok;
    GLOAD16(Kg + (size_t)tok * 64 + (q << 3), Ks + c * 16);
  }
#pragma unroll
  for (int it = 0; it < 4; ++it) {
    int c = tid + (it << 8);
    int r = c >> 4, p = c & 15, q = p ^ (r & 7);
    int tk = t0 + (q << 3);
    tk = tk < 0 ? 0 : tk;
    GLOAD16(Vg + (size_t)r * 2048 + tk, Vs + c * 16);
  }
  __syncthreads();

  f32x4 sc[8] = {};
  bf16x8 qf[2];
#pragma unroll
  for (int kk = 0; kk < 2; ++kk) {
    int r = (w << 4) + colL;
    int slot = (kk << 2) + g;
    qf[kk] = *(const bf16x8*)(Qs + r * 128 + ((slot ^ (r & 7)) << 4));
  }
#pragma unroll
  for (int ni = 0; ni < 8; ++ni) {
#pragma unroll
    for (int kk = 0; kk < 2; ++kk) {
      int r = (ni << 4) + colL;
      int slot = (kk << 2) + g;
      bf16x8 kf = *(const bf16x8*)(Ks + r * 128 + ((slot ^ (r & 7)) << 4));
      sc[ni] = MFMA16(qf[kk], kf, sc[ni]);
    }
  }

  float mx[4], sm[4];
#pragma unroll
  for (int j = 0; j < 4; ++j) mx[j] = -3.0e38f;
#pragma unroll
  for (int ni = 0; ni < 8; ++ni) {
#pragma unroll
    for (int j = 0; j < 4; ++j) {
      const int qi = (w << 4) + (g << 2) + j;
      const int ki = (ni << 4) + colL;
      const bool valid = (ki > qi) && (ki <= qi + 64) && (qb > 0 || ki >= 64);
      if (!valid) sc[ni][j] = -3.0e38f;
      mx[j] = fmaxf(mx[j], sc[ni][j]);
    }
  }
#pragma unroll
  for (int j = 0; j < 4; ++j) {
    mx[j] = fmaxf(mx[j], __shfl_xor(mx[j], 1));
    mx[j] = fmaxf(mx[j], __shfl_xor(mx[j], 2));
    mx[j] = fmaxf(mx[j], __shfl_xor(mx[j], 4));
    mx[j] = fmaxf(mx[j], __shfl_xor(mx[j], 8));
    sm[j] = 0.0f;
  }
  unsigned char* ps = Ps + w * (16 * 272);
#pragma unroll
  for (int ni = 0; ni < 8; ++ni) {
#pragma unroll
    for (int j = 0; j < 4; ++j) {
      float p = __expf(sc[ni][j] - mx[j]);
      sm[j] += p;
      *(__bf16*)(ps + ((g << 2) + j) * 272 + (((ni << 4) + colL) << 1)) = (__bf16)p;
    }
  }
#pragma unroll
  for (int j = 0; j < 4; ++j) {
    sm[j] += __shfl_xor(sm[j], 1);
    sm[j] += __shfl_xor(sm[j], 2);
    sm[j] += __shfl_xor(sm[j], 4);
    sm[j] += __shfl_xor(sm[j], 8);
  }
  __syncthreads();

  f32x4 o[4] = {};
#pragma unroll
  for (int step = 0; step < 4; ++step) {
    bf16x8 pf = *(const bf16x8*)(ps + colL * 272 + (step << 6) + (g << 4));
#pragma unroll
    for (int dt = 0; dt < 4; ++dt) {
      int r = (dt << 4) + colL;
      int slot = (step << 2) + g;
      bf16x8 vf = *(const bf16x8*)(Vs + r * 256 + ((slot ^ (r & 7)) << 4));
      o[dt] = MFMA16(pf, vf, o[dt]);
    }
  }

  float rinv[4];
#pragma unroll
  for (int j = 0; j < 4; ++j) rinv[j] = 1.0f / sm[j];
#pragma unroll
  for (int dt = 0; dt < 4; ++dt) {
#pragma unroll
    for (int j = 0; j < 4; ++j) {
      const int t = qb * 64 + (w << 4) + (g << 2) + j;
      Ob[((size_t)b * 2048 + t) * 1024 + h * 64 + (dt << 4) + colL] =
          (__bf16)(o[dt][j] * rinv[j]);
    }
  }
}

extern "C" void kernel_launch(void* const* d_in, const int* in_sizes, int n_in,
                              void* d_out, int out_size, void* d_ws, size_t ws_size,
                              hipStream_t stream) {
  const float* x = (const float*)d_in[0];     // [2,2048,1024]
  const float* Wqkv = (const float*)d_in[1];  // [3072,1024]
  const float* bqkv = (const float*)d_in[2];  // [3072]
  const float* Wout = (const float*)d_in[3];  // [1024,1024]
  const float* bout = (const float*)d_in[4];  // [1024]
  float* out = (float*)d_out;                 // [2,2048,1024] fp32

  __bf16* xb = (__bf16*)d_ws;             // 4194304
  __bf16* Wqkvb = xb + 4194304;           // 3145728
  __bf16* Woutb = Wqkvb + 3145728;        // 1048576
  __bf16* Qb = Woutb + 1048576;           // 4194304 each: [B,H,2048,64]
  __bf16* Kb = Qb + 4194304;
  __bf16* Vtb = Kb + 4194304;             // [B,H,64,2048] (written transposed by gemm)
  __bf16* AOb = Vtb + 4194304;            // attn out [B,2048,1024]

  cvt3<<<4096, 256, 0, stream>>>(x, Wqkv, Wout, xb, Wqkvb, Woutb);
  gemm_qkv<<<768, 256, 0, stream>>>(xb, Wqkvb, bqkv, Qb, Kb, Vtb);
  attn_win<<<1024, 256, 0, stream>>>(Qb, Kb, Vtb, AOb);
  gemm_out<<<512, 128, 0, stream>>>(AOb, Woutb, bout, 1024, out, 8, 64);
}

// Round 14
// 74.514 us; speedup vs baseline: 1.2941x; 1.0447x over previous
//
#include <hip/hip_runtime.h>
#include <hip/hip_bf16.h>

// LocalCausalAttention: B=2, N=2048, D=1024, H=16, DH=64, WINDOW=64
// out = ( softmax(mask(QK^T*0.125)) V ) Wout^T + bout,  QKV = x Wqkv^T + bqkv
//
// R14: attn-only round (QKV = R13 champion verbatim: 41.2us, 627 TF).
//   attn_win changes:
//   1. Ps ALIASED into dead Qs/Ks region after QK^T (extra __syncthreads makes
//      it race-free): LDS 66.5KB -> 40KB -> 4 blocks/CU (was 2).
//   2. XCD chunking on grid (1024 = 128/XCD, bijective): consecutive qb blocks
//      (sharing a 64-token K/V half tile) now land on the same XCD L2.
//   gemm_out / cvt3 unchanged (R8-verified).

typedef __attribute__((ext_vector_type(8))) __bf16 bf16x8;
typedef __attribute__((ext_vector_type(4))) float f32x4;

#define GLOAD16(g, l)                                              \
  __builtin_amdgcn_global_load_lds(                                \
      (const __attribute__((address_space(1))) void*)(g),          \
      (__attribute__((address_space(3))) void*)(l), 16, 0, 0)

#define MFMA16(a, b, c) __builtin_amdgcn_mfma_f32_16x16x32_bf16((a), (b), (c), 0, 0, 0)

// ---------------- fused fp32 -> bf16 convert (x, Wqkv, Wout) ----------------
__global__ __launch_bounds__(256) void cvt3(const float* __restrict__ x,
                                            const float* __restrict__ wqkv,
                                            const float* __restrict__ wout,
                                            __bf16* __restrict__ xb,
                                            __bf16* __restrict__ wqkvb,
                                            __bf16* __restrict__ woutb) {
  const int blk = blockIdx.x;
  const float* src;
  __bf16* dst;
  int i;
  if (blk < 2048) {            // x: 4194304 elems
    src = x; dst = xb; i = (blk * 256 + (int)threadIdx.x) * 8;
  } else if (blk < 3584) {     // Wqkv: 3145728 elems
    src = wqkv; dst = wqkvb; i = ((blk - 2048) * 256 + (int)threadIdx.x) * 8;
  } else {                     // Wout: 1048576 elems
    src = wout; dst = woutb; i = ((blk - 3584) * 256 + (int)threadIdx.x) * 8;
  }
  f32x4 a = *(const f32x4*)(src + i);
  f32x4 b = *(const f32x4*)(src + i + 4);
  bf16x8 o;
  o[0] = (__bf16)a[0]; o[1] = (__bf16)a[1]; o[2] = (__bf16)a[2]; o[3] = (__bf16)a[3];
  o[4] = (__bf16)b[0]; o[5] = (__bf16)b[1]; o[6] = (__bf16)b[2]; o[7] = (__bf16)b[3];
  *(bf16x8*)(dst + i) = o;
}

// ---------------- 128^2 BK=32 counted-vmcnt QKV GEMM (R13 champion verbatim) ----------------
// C[m,n] = sum_k A[m,k]*Wqkv[n,k] + bqkv[n]; M=4096,N=3072,K=1024 fixed.
// 4 waves (2x2), per-wave 64x64. LDS exactly 32768: 2x16KB bufs, epilogue aliases them.
__global__ __launch_bounds__(256) void gemm_qkv(
    const __bf16* __restrict__ A, const __bf16* __restrict__ Bw,
    const float* __restrict__ bias,
    __bf16* __restrict__ qo, __bf16* __restrict__ ko, __bf16* __restrict__ vt) {
  constexpr int K = 1024;
  __shared__ __align__(16) unsigned char Ls[32768];
  const int tid = threadIdx.x;
  const int lane = tid & 63;
  const int wid = tid >> 6;
  const int wr = wid >> 1, wc = wid & 1;
  const int colL = lane & 15, g = lane >> 4;

  // 1D XCD chunking (R6-exact): 768 blocks = 96/XCD, n fastest within chunk
  int s = (int)blockIdx.x;
  s = (s & 7) * 96 + (s >> 3);
  const int m0 = (s / 24) * 128, n0 = (s % 24) * 128;

  const __bf16* Ap = A + (size_t)m0 * K;
  const __bf16* Bp = Bw + (size_t)n0 * K;

  // stage one matrix half-step (128 rows x 32 cols = 8KB), paired-row layout:
  // linear LDS dest c*16; line L=c>>3, s6=c&7; u=s6^(L&7) -> row=2L+(u>>2), p=u&3.
  auto stage2 = [&](const __bf16* src, unsigned char* lds, int k0) {
#pragma unroll
    for (int it = 0; it < 2; ++it) {
      int c = tid + (it << 8);       // 0..511
      int L = c >> 3, s6 = c & 7;
      int u = s6 ^ (L & 7);
      int row = (L << 1) | (u >> 2), p = u & 3;
      GLOAD16(src + (size_t)row * K + k0 + (p << 3), lds + c * 16);
    }
  };

  f32x4 acc[4][4] = {};

  // prologue: tiles 0,1 into bufs 0,1
  stage2(Ap, Ls, 0);
  stage2(Bp, Ls + 8192, 0);
  stage2(Ap, Ls + 16384, 32);
  stage2(Bp, Ls + 24576, 32);
  asm volatile("s_waitcnt vmcnt(4)" ::: "memory");  // tile0 landed; tile1 in flight
  __builtin_amdgcn_s_barrier();

  const int nT = K >> 5;  // 32 steps
  for (int t = 0; t < nT; ++t) {
    const unsigned char* Ab = Ls + (t & 1) * 16384;
    const unsigned char* Bb = Ab + 8192;
    bf16x8 af[4], bf[4];
#pragma unroll
    for (int mi = 0; mi < 4; ++mi) {
      const int r = (wr << 6) + (mi << 4) + colL;
      af[mi] = *(const bf16x8*)(Ab + (r >> 1) * 128 +
                                (((((r & 1) << 2) | g) ^ ((r >> 1) & 7)) << 4));
    }
#pragma unroll
    for (int ni = 0; ni < 4; ++ni) {
      const int r = (wc << 6) + (ni << 4) + colL;
      bf[ni] = *(const bf16x8*)(Bb + (r >> 1) * 128 +
                                (((((r & 1) << 2) | g) ^ ((r >> 1) & 7)) << 4));
    }
#pragma unroll
    for (int mi = 0; mi < 4; ++mi)
#pragma unroll
      for (int ni = 0; ni < 4; ++ni)
        acc[mi][ni] = MFMA16(af[mi], bf[ni], acc[mi][ni]);
    // all this wave's ds_reads executed before anyone may DMA-overwrite buf[cur]
    asm volatile("s_waitcnt lgkmcnt(0)" ::: "memory");
    __builtin_amdgcn_s_barrier();
    if (t < nT - 2) {
      const int kn = (t + 2) << 5;
      unsigned char* dst = Ls + (t & 1) * 16384;  // overwrite just-retired buffer
      stage2(Ap, dst, kn);
      stage2(Bp, dst + 8192, kn);
      // in flight: tile t+1 (4) + tile t+2 (4); retire oldest 4 -> t+1 validated
      asm volatile("s_waitcnt vmcnt(4)" ::: "memory");
    } else {
      asm volatile("s_waitcnt vmcnt(0)" ::: "memory");  // tail: drain last tile
    }
    __builtin_amdgcn_s_barrier();
  }

  // epilogue: C/D layout col=lane&15, row=(lane>>4)*4+reg (m89-verified)
  const int Cn0 = n0 + (wc << 6);              // wave's 64-col half: sx/h const
  const int sx = Cn0 >> 10, h = (Cn0 >> 6) & 15;
  float bv[4];
#pragma unroll
  for (int ni = 0; ni < 4; ++ni) bv[ni] = bias[Cn0 + (ni << 4) + colL];
  const int b = m0 >> 11;
  if (sx == 2) {
    // ---- V: transpose via ALIASED swizzled LDS scratch (8KB/wave in Ls) ----
    unsigned char* wreg = Ls + wid * 8192;     // per-wave [64 d][64 tt] u16, XOR-swz
#pragma unroll
    for (int mi = 0; mi < 4; ++mi)
#pragma unroll
      for (int ni = 0; ni < 4; ++ni)
#pragma unroll
        for (int jp = 0; jp < 2; ++jp) {
          const int tt = (mi << 4) + (g << 2) + (jp << 1);
          const int d = (ni << 4) + colL;
          unsigned short u0 = __builtin_bit_cast(
              unsigned short, (__bf16)(acc[mi][ni][jp * 2] + bv[ni]));
          unsigned short u1 = __builtin_bit_cast(
              unsigned short, (__bf16)(acc[mi][ni][jp * 2 + 1] + bv[ni]));
          *(unsigned int*)(wreg + (d << 7) + (((tt << 1) ^ ((d & 7) << 4)))) =
              (unsigned int)u0 | ((unsigned int)u1 << 16);
        }
    asm volatile("s_waitcnt lgkmcnt(0)" ::: "memory");
    const size_t vbase = (size_t)(b * 16 + h) * 64 * 2048;
    const int tg0 = (m0 & 2047) + (wr << 6);
#pragma unroll
    for (int i2 = 0; i2 < 32; ++i2) {
      const int d = (i2 << 1) + (lane >> 5);
      const int toff = (lane & 31) << 1;
      unsigned int v = *(unsigned int*)(wreg + (d << 7) +
                                        ((((lane & 31) << 2)) ^ ((d & 7) << 4)));
      *(unsigned int*)((unsigned short*)vt + vbase + (size_t)d * 2048 + tg0 + toff) = v;
    }
  } else {
    __bf16* dst = (sx == 0) ? qo : ko;
    const float mul = (sx == 0) ? 0.125f : 1.0f;  // fold SCALE into Q (exact pow2)
#pragma unroll
    for (int mi = 0; mi < 4; ++mi) {
#pragma unroll
      for (int j = 0; j < 4; ++j) {
        const int Rm = m0 + (wr << 6) + (mi << 4) + (g << 2) + j;
        const int tt = Rm & 2047;
        __bf16* rowp = dst + (((size_t)b * 16 + h) * 2048 + tt) * 64;
#pragma unroll
        for (int ni = 0; ni < 4; ++ni)  // 4 x 32B bursts -> full 128B line
          rowp[(ni << 4) + colL] = (__bf16)((acc[mi][ni][j] + bv[ni]) * mul);
      }
    }
  }
}

// ---------------- 64x128 BK=64 counted-vmcnt dbuf GEMM (out-proj, R8-verified) ----------------
__global__ __launch_bounds__(128) void gemm_out(
    const __bf16* __restrict__ A, const __bf16* __restrict__ Bw,
    const float* __restrict__ bias, int N,
    float* __restrict__ outF, int nbn, int chunk) {
  constexpr int K = 1024;
  constexpr int ASZ = 8192;          // A half: 64 rows x 128B
  constexpr int BUF = ASZ + 16384;   // + B half: 128 rows x 128B
  __shared__ __align__(16) unsigned char Ls[2 * BUF];
  const int tid = threadIdx.x;
  const int lane = tid & 63;
  const int wc = tid >> 6;
  const int colL = lane & 15, g = lane >> 4;

  int s = (int)blockIdx.x;
  s = (s & 7) * chunk + (s >> 3);
  const int m0 = (s / nbn) * 64, n0 = (s % nbn) * 128;

  const __bf16* Ap = A + (size_t)m0 * K;
  const __bf16* Bp = Bw + (size_t)n0 * K;

  auto stageA = [&](unsigned char* lds, int k0) {
#pragma unroll
    for (int it = 0; it < 4; ++it) {
      int c = tid + it * 128;
      int row = c >> 3, p = c & 7, q = p ^ (row & 7);
      GLOAD16(Ap + (size_t)row * K + k0 + (q << 3), lds + c * 16);
    }
  };
  auto stageB = [&](unsigned char* lds, int k0) {
#pragma unroll
    for (int it = 0; it < 8; ++it) {
      int c = tid + it * 128;
      int row = c >> 3, p = c & 7, q = p ^ (row & 7);
      GLOAD16(Bp + (size_t)row * K + k0 + (q << 3), lds + c * 16);
    }
  };

  f32x4 acc[4][4] = {};

  stageA(Ls, 0);
  stageB(Ls + ASZ, 0);
  stageA(Ls + BUF, 64);
  stageB(Ls + BUF + ASZ, 64);
  asm volatile("s_waitcnt vmcnt(12)" ::: "memory");
  __builtin_amdgcn_s_barrier();

  constexpr int nT = 16;
  for (int t = 0; t < nT; ++t) {
    const unsigned char* Ab = Ls + (t & 1) * BUF;
    const unsigned char* Bb = Ab + ASZ;
    bf16x8 af[4][2], bf[4][2];
#pragma unroll
    for (int mi = 0; mi < 4; ++mi) {
      const int r = (mi << 4) + colL;
#pragma unroll
      for (int kk = 0; kk < 2; ++kk)
        af[mi][kk] = *(const bf16x8*)(Ab + r * 128 + ((((kk << 2) + g) ^ (r & 7)) << 4));
    }
#pragma unroll
    for (int ni = 0; ni < 4; ++ni) {
      const int r = (wc << 6) + (ni << 4) + colL;
#pragma unroll
      for (int kk = 0; kk < 2; ++kk)
        bf[ni][kk] = *(const bf16x8*)(Bb + r * 128 + ((((kk << 2) + g) ^ (r & 7)) << 4));
    }
#pragma unroll
    for (int mi = 0; mi < 4; ++mi)
#pragma unroll
      for (int ni = 0; ni < 4; ++ni) {
        acc[mi][ni] = MFMA16(af[mi][0], bf[ni][0], acc[mi][ni]);
        acc[mi][ni] = MFMA16(af[mi][1], bf[ni][1], acc[mi][ni]);
      }
    asm volatile("s_waitcnt lgkmcnt(0)" ::: "memory");
    __builtin_amdgcn_s_barrier();
    if (t < nT - 2) {
      const int kn = (t + 2) << 6;
      unsigned char* dst = Ls + (t & 1) * BUF;
      stageA(dst, kn);
      stageB(dst + ASZ, kn);
      asm volatile("s_waitcnt vmcnt(12)" ::: "memory");
    } else {
      asm volatile("s_waitcnt vmcnt(0)" ::: "memory");
    }
    __builtin_amdgcn_s_barrier();
  }

  float bv[4];
#pragma unroll
  for (int ni = 0; ni < 4; ++ni) bv[ni] = bias[n0 + (wc << 6) + (ni << 4) + colL];
#pragma unroll
  for (int mi = 0; mi < 4; ++mi) {
#pragma unroll
    for (int j = 0; j < 4; ++j) {
      const int Rm = m0 + (mi << 4) + (g << 2) + j;
      float* rowp = outF + (size_t)Rm * N + n0 + (wc << 6);
#pragma unroll
      for (int ni = 0; ni < 4; ++ni)
        rowp[(ni << 4) + colL] = acc[mi][ni][j] + bv[ni];
    }
  }
}

// ---------------- windowed attention (R14: 40KB LDS via Ps-alias + XCD chunk) ----------------
__global__ __launch_bounds__(256) void attn_win(const __bf16* __restrict__ Qb,
                                                const __bf16* __restrict__ Kb,
                                                const __bf16* __restrict__ Vt,
                                                __bf16* __restrict__ Ob) {
  // XCD chunking: 1024 blocks = 128/XCD (bijective); consecutive (bh,qb) share K/V in L2
  const int sblk = ((int)blockIdx.x & 7) * 128 + ((int)blockIdx.x >> 3);
  const int bh = sblk >> 5;
  const int qb = sblk & 31;
  const int b = bh >> 4, h = bh & 15;
  __shared__ __align__(16) unsigned char Ls[40960];  // Qs 8K | Ks 16K | Vs 16K
  unsigned char* Qs = Ls;
  unsigned char* Ks = Ls + 8192;
  unsigned char* Vs = Ls + 24576;
  const int tid = threadIdx.x;
  const int lane = tid & 63;
  const int w = tid >> 6;
  const int colL = lane & 15, g = lane >> 4;
  const __bf16* Qg = Qb + (size_t)bh * 2048 * 64;
  const __bf16* Kg = Kb + (size_t)bh * 2048 * 64;
  const __bf16* Vg = Vt + (size_t)bh * 64 * 2048;
  const int t0 = qb * 64 - 64;

#pragma unroll
  for (int it = 0; it < 2; ++it) {
    int c = tid + (it << 8);
    int r = c >> 3, p = c & 7, q = p ^ (r & 7);
    GLOAD16(Qg + (size_t)(qb * 64 + r) * 64 + (q << 3), Qs + c * 16);
  }
#pragma unroll
  for (int it = 0; it < 4; ++it) {
    int c = tid + (it << 8);
    int r = c >> 3, p = c & 7, q = p ^ (r & 7);
    int tok = t0 + r;
    tok = tok < 0 ? 0 : tok;
    GLOAD16(Kg + (size_t)tok * 64 + (q << 3), Ks + c * 16);
  }
#pragma unroll
  for (int it = 0; it < 4; ++it) {
    int c = tid + (it << 8);
    int r = c >> 4, p = c & 15, q = p ^ (r & 7);
    int tk = t0 + (q << 3);
    tk = tk < 0 ? 0 : tk;
    GLOAD16(Vg + (size_t)r * 2048 + tk, Vs + c * 16);
  }
  __syncthreads();

  f32x4 sc[8] = {};
  bf16x8 qf[2];
#pragma unroll
  for (int kk = 0; kk < 2; ++kk) {
    int r = (w << 4) + colL;
    int slot = (kk << 2) + g;
    qf[kk] = *(const bf16x8*)(Qs + r * 128 + ((slot ^ (r & 7)) << 4));
  }
#pragma unroll
  for (int ni = 0; ni < 8; ++ni) {
#pragma unroll
    for (int kk = 0; kk < 2; ++kk) {
      int r = (ni << 4) + colL;
      int slot = (kk << 2) + g;
      bf16x8 kf = *(const bf16x8*)(Ks + r * 128 + ((slot ^ (r & 7)) << 4));
      sc[ni] = MFMA16(qf[kk], kf, sc[ni]);
    }
  }

  float mx[4], sm[4];
#pragma unroll
  for (int j = 0; j < 4; ++j) mx[j] = -3.0e38f;
#pragma unroll
  for (int ni = 0; ni < 8; ++ni) {
#pragma unroll
    for (int j = 0; j < 4; ++j) {
      const int qi = (w << 4) + (g << 2) + j;
      const int ki = (ni << 4) + colL;
      const bool valid = (ki > qi) && (ki <= qi + 64) && (qb > 0 || ki >= 64);
      if (!valid) sc[ni][j] = -3.0e38f;
      mx[j] = fmaxf(mx[j], sc[ni][j]);
    }
  }
#pragma unroll
  for (int j = 0; j < 4; ++j) {
    mx[j] = fmaxf(mx[j], __shfl_xor(mx[j], 1));
    mx[j] = fmaxf(mx[j], __shfl_xor(mx[j], 2));
    mx[j] = fmaxf(mx[j], __shfl_xor(mx[j], 4));
    mx[j] = fmaxf(mx[j], __shfl_xor(mx[j], 8));
    sm[j] = 0.0f;
  }
  // Qs/Ks now dead everywhere: barrier (drains every wave's ds_reads) before
  // aliasing their region as the P buffer.
  __syncthreads();
  unsigned char* ps = Ls + w * 4352;  // per-wave 16 rows x 272B, region [0,17408)
#pragma unroll
  for (int ni = 0; ni < 8; ++ni) {
#pragma unroll
    for (int j = 0; j < 4; ++j) {
      float p = __expf(sc[ni][j] - mx[j]);
      sm[j] += p;
      *(__bf16*)(ps + ((g << 2) + j) * 272 + (((ni << 4) + colL) << 1)) = (__bf16)p;
    }
  }
#pragma unroll
  for (int j = 0; j < 4; ++j) {
    sm[j] += __shfl_xor(sm[j], 1);
    sm[j] += __shfl_xor(sm[j], 2);
    sm[j] += __shfl_xor(sm[j], 4);
    sm[j] += __shfl_xor(sm[j], 8);
  }
  __syncthreads();

  f32x4 o[4] = {};
#pragma unroll
  for (int step = 0; step < 4; ++step) {
    bf16x8 pf = *(const bf16x8*)(ps + colL * 272 + (step << 6) + (g << 4));
#pragma unroll
    for (int dt = 0; dt < 4; ++dt) {
      int r = (dt << 4) + colL;
      int slot = (step << 2) + g;
      bf16x8 vf = *(const bf16x8*)(Vs + r * 256 + ((slot ^ (r & 7)) << 4));
      o[dt] = MFMA16(pf, vf, o[dt]);
    }
  }

  float rinv[4];
#pragma unroll
  for (int j = 0; j < 4; ++j) rinv[j] = 1.0f / sm[j];
#pragma unroll
  for (int dt = 0; dt < 4; ++dt) {
#pragma unroll
    for (int j = 0; j < 4; ++j) {
      const int t = qb * 64 + (w << 4) + (g << 2) + j;
      Ob[((size_t)b * 2048 + t) * 1024 + h * 64 + (dt << 4) + colL] =
          (__bf16)(o[dt][j] * rinv[j]);
    }
  }
}

extern "C" void kernel_launch(void* const* d_in, const int* in_sizes, int n_in,
                              void* d_out, int out_size, void* d_ws, size_t ws_size,
                              hipStream_t stream) {
  const float* x = (const float*)d_in[0];     // [2,2048,1024]
  const float* Wqkv = (const float*)d_in[1];  // [3072,1024]
  const float* bqkv = (const float*)d_in[2];  // [3072]
  const float* Wout = (const float*)d_in[3];  // [1024,1024]
  const float* bout = (const float*)d_in[4];  // [1024]
  float* out = (float*)d_out;                 // [2,2048,1024] fp32

  __bf16* xb = (__bf16*)d_ws;             // 4194304
  __bf16* Wqkvb = xb + 4194304;           // 3145728
  __bf16* Woutb = Wqkvb + 3145728;        // 1048576
  __bf16* Qb = Woutb + 1048576;           // 4194304 each: [B,H,2048,64]
  __bf16* Kb = Qb + 4194304;
  __bf16* Vtb = Kb + 4194304;             // [B,H,64,2048] (written transposed by gemm)
  __bf16* AOb = Vtb + 4194304;            // attn out [B,2048,1024]

  cvt3<<<4096, 256, 0, stream>>>(x, Wqkv, Wout, xb, Wqkvb, Woutb);
  gemm_qkv<<<768, 256, 0, stream>>>(xb, Wqkvb, bqkv, Qb, Kb, Vtb);
  attn_win<<<1024, 256, 0, stream>>>(Qb, Kb, Vtb, AOb);
  gemm_out<<<512, 128, 0, stream>>>(AOb, Woutb, bout, 1024, out, 8, 64);
}

// Round 15
// 74.125 us; speedup vs baseline: 1.3008x; 1.0052x over previous
//
#include <hip/hip_runtime.h>
#include <hip/hip_bf16.h>

// LocalCausalAttention: B=2, N=2048, D=1024, H=16, DH=64, WINDOW=64
// out = ( softmax(mask(QK^T*0.125)) V ) Wout^T + bout,  QKV = x Wqkv^T + bqkv
//
// R15: gemm_out-only round (everything else = R14 verbatim; QKV champion 41.2us).
//   gemm_out was 128 threads -> 4 waves/CU (1/SIMD), the pipeline's lowest TLP.
//   New: same 64x128 tile + BK=32 counted-vmcnt dbuf (R6-verified ledger), but
//   256 threads (4 waves, 1M x 4N, per-wave 64x32 = acc[4][2]), LDS 24KB
//   -> 2 blocks/CU x 4 waves = 8 waves/CU. Staging 3 gloads/thread/tile ->
//   vmcnt(3) validates t+1 with t+2 in flight. 2D XCD chunk (8m x 8n per XCD:
//   A 1MB + B 2MB = 3MB < 4MB L2).

typedef __attribute__((ext_vector_type(8))) __bf16 bf16x8;
typedef __attribute__((ext_vector_type(4))) float f32x4;

#define GLOAD16(g, l)                                              \
  __builtin_amdgcn_global_load_lds(                                \
      (const __attribute__((address_space(1))) void*)(g),          \
      (__attribute__((address_space(3))) void*)(l), 16, 0, 0)

#define MFMA16(a, b, c) __builtin_amdgcn_mfma_f32_16x16x32_bf16((a), (b), (c), 0, 0, 0)

// ---------------- fused fp32 -> bf16 convert (x, Wqkv, Wout) ----------------
__global__ __launch_bounds__(256) void cvt3(const float* __restrict__ x,
                                            const float* __restrict__ wqkv,
                                            const float* __restrict__ wout,
                                            __bf16* __restrict__ xb,
                                            __bf16* __restrict__ wqkvb,
                                            __bf16* __restrict__ woutb) {
  const int blk = blockIdx.x;
  const float* src;
  __bf16* dst;
  int i;
  if (blk < 2048) {            // x: 4194304 elems
    src = x; dst = xb; i = (blk * 256 + (int)threadIdx.x) * 8;
  } else if (blk < 3584) {     // Wqkv: 3145728 elems
    src = wqkv; dst = wqkvb; i = ((blk - 2048) * 256 + (int)threadIdx.x) * 8;
  } else {                     // Wout: 1048576 elems
    src = wout; dst = woutb; i = ((blk - 3584) * 256 + (int)threadIdx.x) * 8;
  }
  f32x4 a = *(const f32x4*)(src + i);
  f32x4 b = *(const f32x4*)(src + i + 4);
  bf16x8 o;
  o[0] = (__bf16)a[0]; o[1] = (__bf16)a[1]; o[2] = (__bf16)a[2]; o[3] = (__bf16)a[3];
  o[4] = (__bf16)b[0]; o[5] = (__bf16)b[1]; o[6] = (__bf16)b[2]; o[7] = (__bf16)b[3];
  *(bf16x8*)(dst + i) = o;
}

// ---------------- 128^2 BK=32 counted-vmcnt QKV GEMM (R13 champion verbatim) ----------------
__global__ __launch_bounds__(256) void gemm_qkv(
    const __bf16* __restrict__ A, const __bf16* __restrict__ Bw,
    const float* __restrict__ bias,
    __bf16* __restrict__ qo, __bf16* __restrict__ ko, __bf16* __restrict__ vt) {
  constexpr int K = 1024;
  __shared__ __align__(16) unsigned char Ls[32768];
  const int tid = threadIdx.x;
  const int lane = tid & 63;
  const int wid = tid >> 6;
  const int wr = wid >> 1, wc = wid & 1;
  const int colL = lane & 15, g = lane >> 4;

  // 1D XCD chunking (R6-exact): 768 blocks = 96/XCD, n fastest within chunk
  int s = (int)blockIdx.x;
  s = (s & 7) * 96 + (s >> 3);
  const int m0 = (s / 24) * 128, n0 = (s % 24) * 128;

  const __bf16* Ap = A + (size_t)m0 * K;
  const __bf16* Bp = Bw + (size_t)n0 * K;

  // stage one matrix half-step (128 rows x 32 cols = 8KB), paired-row layout:
  // linear LDS dest c*16; line L=c>>3, s6=c&7; u=s6^(L&7) -> row=2L+(u>>2), p=u&3.
  auto stage2 = [&](const __bf16* src, unsigned char* lds, int k0) {
#pragma unroll
    for (int it = 0; it < 2; ++it) {
      int c = tid + (it << 8);       // 0..511
      int L = c >> 3, s6 = c & 7;
      int u = s6 ^ (L & 7);
      int row = (L << 1) | (u >> 2), p = u & 3;
      GLOAD16(src + (size_t)row * K + k0 + (p << 3), lds + c * 16);
    }
  };

  f32x4 acc[4][4] = {};

  // prologue: tiles 0,1 into bufs 0,1
  stage2(Ap, Ls, 0);
  stage2(Bp, Ls + 8192, 0);
  stage2(Ap, Ls + 16384, 32);
  stage2(Bp, Ls + 24576, 32);
  asm volatile("s_waitcnt vmcnt(4)" ::: "memory");  // tile0 landed; tile1 in flight
  __builtin_amdgcn_s_barrier();

  const int nT = K >> 5;  // 32 steps
  for (int t = 0; t < nT; ++t) {
    const unsigned char* Ab = Ls + (t & 1) * 16384;
    const unsigned char* Bb = Ab + 8192;
    bf16x8 af[4], bf[4];
#pragma unroll
    for (int mi = 0; mi < 4; ++mi) {
      const int r = (wr << 6) + (mi << 4) + colL;
      af[mi] = *(const bf16x8*)(Ab + (r >> 1) * 128 +
                                (((((r & 1) << 2) | g) ^ ((r >> 1) & 7)) << 4));
    }
#pragma unroll
    for (int ni = 0; ni < 4; ++ni) {
      const int r = (wc << 6) + (ni << 4) + colL;
      bf[ni] = *(const bf16x8*)(Bb + (r >> 1) * 128 +
                                (((((r & 1) << 2) | g) ^ ((r >> 1) & 7)) << 4));
    }
#pragma unroll
    for (int mi = 0; mi < 4; ++mi)
#pragma unroll
      for (int ni = 0; ni < 4; ++ni)
        acc[mi][ni] = MFMA16(af[mi], bf[ni], acc[mi][ni]);
    // all this wave's ds_reads executed before anyone may DMA-overwrite buf[cur]
    asm volatile("s_waitcnt lgkmcnt(0)" ::: "memory");
    __builtin_amdgcn_s_barrier();
    if (t < nT - 2) {
      const int kn = (t + 2) << 5;
      unsigned char* dst = Ls + (t & 1) * 16384;  // overwrite just-retired buffer
      stage2(Ap, dst, kn);
      stage2(Bp, dst + 8192, kn);
      // in flight: tile t+1 (4) + tile t+2 (4); retire oldest 4 -> t+1 validated
      asm volatile("s_waitcnt vmcnt(4)" ::: "memory");
    } else {
      asm volatile("s_waitcnt vmcnt(0)" ::: "memory");  // tail: drain last tile
    }
    __builtin_amdgcn_s_barrier();
  }

  // epilogue: C/D layout col=lane&15, row=(lane>>4)*4+reg (m89-verified)
  const int Cn0 = n0 + (wc << 6);              // wave's 64-col half: sx/h const
  const int sx = Cn0 >> 10, h = (Cn0 >> 6) & 15;
  float bv[4];
#pragma unroll
  for (int ni = 0; ni < 4; ++ni) bv[ni] = bias[Cn0 + (ni << 4) + colL];
  const int b = m0 >> 11;
  if (sx == 2) {
    // ---- V: transpose via ALIASED swizzled LDS scratch (8KB/wave in Ls) ----
    unsigned char* wreg = Ls + wid * 8192;     // per-wave [64 d][64 tt] u16, XOR-swz
#pragma unroll
    for (int mi = 0; mi < 4; ++mi)
#pragma unroll
      for (int ni = 0; ni < 4; ++ni)
#pragma unroll
        for (int jp = 0; jp < 2; ++jp) {
          const int tt = (mi << 4) + (g << 2) + (jp << 1);
          const int d = (ni << 4) + colL;
          unsigned short u0 = __builtin_bit_cast(
              unsigned short, (__bf16)(acc[mi][ni][jp * 2] + bv[ni]));
          unsigned short u1 = __builtin_bit_cast(
              unsigned short, (__bf16)(acc[mi][ni][jp * 2 + 1] + bv[ni]));
          *(unsigned int*)(wreg + (d << 7) + (((tt << 1) ^ ((d & 7) << 4)))) =
              (unsigned int)u0 | ((unsigned int)u1 << 16);
        }
    asm volatile("s_waitcnt lgkmcnt(0)" ::: "memory");
    const size_t vbase = (size_t)(b * 16 + h) * 64 * 2048;
    const int tg0 = (m0 & 2047) + (wr << 6);
#pragma unroll
    for (int i2 = 0; i2 < 32; ++i2) {
      const int d = (i2 << 1) + (lane >> 5);
      const int toff = (lane & 31) << 1;
      unsigned int v = *(unsigned int*)(wreg + (d << 7) +
                                        ((((lane & 31) << 2)) ^ ((d & 7) << 4)));
      *(unsigned int*)((unsigned short*)vt + vbase + (size_t)d * 2048 + tg0 + toff) = v;
    }
  } else {
    __bf16* dst = (sx == 0) ? qo : ko;
    const float mul = (sx == 0) ? 0.125f : 1.0f;  // fold SCALE into Q (exact pow2)
#pragma unroll
    for (int mi = 0; mi < 4; ++mi) {
#pragma unroll
      for (int j = 0; j < 4; ++j) {
        const int Rm = m0 + (wr << 6) + (mi << 4) + (g << 2) + j;
        const int tt = Rm & 2047;
        __bf16* rowp = dst + (((size_t)b * 16 + h) * 2048 + tt) * 64;
#pragma unroll
        for (int ni = 0; ni < 4; ++ni)  // 4 x 32B bursts -> full 128B line
          rowp[(ni << 4) + colL] = (__bf16)((acc[mi][ni][j] + bv[ni]) * mul);
      }
    }
  }
}

// ---------------- 64x128 BK=32 counted-vmcnt out-proj, 4 waves (R15) ----------------
// C[m,n] = sum_k A[m,k]*Wout[n,k] + bout[n]; M=4096, N=1024, K=1024.
// 4 waves (1M x 4N), per-wave 64x32 (acc[4][2]). LDS 24KB: [A 4K|B 8K] x 2 bufs.
__global__ __launch_bounds__(256) void gemm_out(
    const __bf16* __restrict__ A, const __bf16* __restrict__ Bw,
    const float* __restrict__ bias, float* __restrict__ outF) {
  constexpr int K = 1024;
  __shared__ __align__(16) unsigned char Ls[24576];
  const int tid = threadIdx.x;
  const int lane = tid & 63;
  const int wc = tid >> 6;              // 0..3: wave n-quarter (32 cols each)
  const int colL = lane & 15, g = lane >> 4;

  // 2D XCD chunk: 512 blocks = 64/XCD; within XCD: 8 m-tiles x 8 n-tiles
  int s = (int)blockIdx.x;
  s = (s & 7) * 64 + (s >> 3);
  const int m0 = (s >> 3) * 64, n0 = (s & 7) * 128;

  const __bf16* Ap = A + (size_t)m0 * K;
  const __bf16* Bp = Bw + (size_t)n0 * K;

  // paired-row layout (R6-verified): chunk c -> line L=c>>3, s6=c&7, u=s6^(L&7),
  // src row=2L+(u>>2), col8 p=u&3; linear LDS dest c*16.
  auto stageA = [&](unsigned char* lds, int k0) {  // 64 rows x 32 cols = 4KB
    int c = tid;
    int L = c >> 3, s6 = c & 7, u = s6 ^ (L & 7);
    int row = (L << 1) | (u >> 2), p = u & 3;
    GLOAD16(Ap + (size_t)row * K + k0 + (p << 3), lds + c * 16);
  };
  auto stageB = [&](unsigned char* lds, int k0) {  // 128 rows x 32 cols = 8KB
#pragma unroll
    for (int it = 0; it < 2; ++it) {
      int c = tid + (it << 8);
      int L = c >> 3, s6 = c & 7, u = s6 ^ (L & 7);
      int row = (L << 1) | (u >> 2), p = u & 3;
      GLOAD16(Bp + (size_t)row * K + k0 + (p << 3), lds + c * 16);
    }
  };

  f32x4 acc[4][2] = {};

  // prologue: tiles 0,1 -> bufs 0,1 (3 load-instrs per tile per thread)
  stageA(Ls, 0);
  stageB(Ls + 4096, 0);
  stageA(Ls + 12288, 32);
  stageB(Ls + 16384, 32);
  asm volatile("s_waitcnt vmcnt(3)" ::: "memory");  // tile0 landed; tile1 in flight
  __builtin_amdgcn_s_barrier();

  for (int t = 0; t < 32; ++t) {
    const unsigned char* Ab = Ls + (t & 1) * 12288;
    const unsigned char* Bb = Ab + 4096;
    bf16x8 af[4], bf[2];
#pragma unroll
    for (int mi = 0; mi < 4; ++mi) {
      const int r = (mi << 4) + colL;  // 0..63 (all waves share A rows)
      af[mi] = *(const bf16x8*)(Ab + (r >> 1) * 128 +
                                (((((r & 1) << 2) | g) ^ ((r >> 1) & 7)) << 4));
    }
#pragma unroll
    for (int ni = 0; ni < 2; ++ni) {
      const int r = (wc << 5) + (ni << 4) + colL;  // 0..127
      bf[ni] = *(const bf16x8*)(Bb + (r >> 1) * 128 +
                                (((((r & 1) << 2) | g) ^ ((r >> 1) & 7)) << 4));
    }
#pragma unroll
    for (int mi = 0; mi < 4; ++mi)
#pragma unroll
      for (int ni = 0; ni < 2; ++ni)
        acc[mi][ni] = MFMA16(af[mi], bf[ni], acc[mi][ni]);
    asm volatile("s_waitcnt lgkmcnt(0)" ::: "memory");
    __builtin_amdgcn_s_barrier();
    if (t < 30) {
      const int kn = (t + 2) << 5;
      unsigned char* dst = Ls + (t & 1) * 12288;  // overwrite just-retired buffer
      stageA(dst, kn);
      stageB(dst + 4096, kn);
      // in flight: t+1 (3) + t+2 (3); retire oldest 3 -> t+1 validated
      asm volatile("s_waitcnt vmcnt(3)" ::: "memory");
    } else {
      asm volatile("s_waitcnt vmcnt(0)" ::: "memory");
    }
    __builtin_amdgcn_s_barrier();
  }

  // epilogue: C/D layout col=lane&15, row=(lane>>4)*4+reg
  float bv[2];
#pragma unroll
  for (int ni = 0; ni < 2; ++ni) bv[ni] = bias[n0 + (wc << 5) + (ni << 4) + colL];
#pragma unroll
  for (int mi = 0; mi < 4; ++mi) {
#pragma unroll
    for (int j = 0; j < 4; ++j) {
      const int Rm = m0 + (mi << 4) + (g << 2) + j;
      float* rowp = outF + (size_t)Rm * 1024 + n0 + (wc << 5);
#pragma unroll
      for (int ni = 0; ni < 2; ++ni)
        rowp[(ni << 4) + colL] = acc[mi][ni][j] + bv[ni];
    }
  }
}

// ---------------- windowed attention (R14-verified: 40KB LDS + XCD chunk) ----------------
__global__ __launch_bounds__(256) void attn_win(const __bf16* __restrict__ Qb,
                                                const __bf16* __restrict__ Kb,
                                                const __bf16* __restrict__ Vt,
                                                __bf16* __restrict__ Ob) {
  const int sblk = ((int)blockIdx.x & 7) * 128 + ((int)blockIdx.x >> 3);
  const int bh = sblk >> 5;
  const int qb = sblk & 31;
  const int b = bh >> 4, h = bh & 15;
  __shared__ __align__(16) unsigned char Ls[40960];  // Qs 8K | Ks 16K | Vs 16K
  unsigned char* Qs = Ls;
  unsigned char* Ks = Ls + 8192;
  unsigned char* Vs = Ls + 24576;
  const int tid = threadIdx.x;
  const int lane = tid & 63;
  const int w = tid >> 6;
  const int colL = lane & 15, g = lane >> 4;
  const __bf16* Qg = Qb + (size_t)bh * 2048 * 64;
  const __bf16* Kg = Kb + (size_t)bh * 2048 * 64;
  const __bf16* Vg = Vt + (size_t)bh * 64 * 2048;
  const int t0 = qb * 64 - 64;

#pragma unroll
  for (int it = 0; it < 2; ++it) {
    int c = tid + (it << 8);
    int r = c >> 3, p = c & 7, q = p ^ (r & 7);
    GLOAD16(Qg + (size_t)(qb * 64 + r) * 64 + (q << 3), Qs + c * 16);
  }
#pragma unroll
  for (int it = 0; it < 4; ++it) {
    int c = tid + (it << 8);
    int r = c >> 3, p = c & 7, q = p ^ (r & 7);
    int tok = t0 + r;
    tok = tok < 0 ? 0 : tok;
    GLOAD16(Kg + (size_t)tok * 64 + (q << 3), Ks + c * 16);
  }
#pragma unroll
  for (int it = 0; it < 4; ++it) {
    int c = tid + (it << 8);
    int r = c >> 4, p = c & 15, q = p ^ (r & 7);
    int tk = t0 + (q << 3);
    tk = tk < 0 ? 0 : tk;
    GLOAD16(Vg + (size_t)r * 2048 + tk, Vs + c * 16);
  }
  __syncthreads();

  f32x4 sc[8] = {};
  bf16x8 qf[2];
#pragma unroll
  for (int kk = 0; kk < 2; ++kk) {
    int r = (w << 4) + colL;
    int slot = (kk << 2) + g;
    qf[kk] = *(const bf16x8*)(Qs + r * 128 + ((slot ^ (r & 7)) << 4));
  }
#pragma unroll
  for (int ni = 0; ni < 8; ++ni) {
#pragma unroll
    for (int kk = 0; kk < 2; ++kk) {
      int r = (ni << 4) + colL;
      int slot = (kk << 2) + g;
      bf16x8 kf = *(const bf16x8*)(Ks + r * 128 + ((slot ^ (r & 7)) << 4));
      sc[ni] = MFMA16(qf[kk], kf, sc[ni]);
    }
  }

  float mx[4], sm[4];
#pragma unroll
  for (int j = 0; j < 4; ++j) mx[j] = -3.0e38f;
#pragma unroll
  for (int ni = 0; ni < 8; ++ni) {
#pragma unroll
    for (int j = 0; j < 4; ++j) {
      const int qi = (w << 4) + (g << 2) + j;
      const int ki = (ni << 4) + colL;
      const bool valid = (ki > qi) && (ki <= qi + 64) && (qb > 0 || ki >= 64);
      if (!valid) sc[ni][j] = -3.0e38f;
      mx[j] = fmaxf(mx[j], sc[ni][j]);
    }
  }
#pragma unroll
  for (int j = 0; j < 4; ++j) {
    mx[j] = fmaxf(mx[j], __shfl_xor(mx[j], 1));
    mx[j] = fmaxf(mx[j], __shfl_xor(mx[j], 2));
    mx[j] = fmaxf(mx[j], __shfl_xor(mx[j], 4));
    mx[j] = fmaxf(mx[j], __shfl_xor(mx[j], 8));
    sm[j] = 0.0f;
  }
  // Qs/Ks dead everywhere: barrier before aliasing their region as P buffer.
  __syncthreads();
  unsigned char* ps = Ls + w * 4352;  // per-wave 16 rows x 272B
#pragma unroll
  for (int ni = 0; ni < 8; ++ni) {
#pragma unroll
    for (int j = 0; j < 4; ++j) {
      float p = __expf(sc[ni][j] - mx[j]);
      sm[j] += p;
      *(__bf16*)(ps + ((g << 2) + j) * 272 + (((ni << 4) + colL) << 1)) = (__bf16)p;
    }
  }
#pragma unroll
  for (int j = 0; j < 4; ++j) {
    sm[j] += __shfl_xor(sm[j], 1);
    sm[j] += __shfl_xor(sm[j], 2);
    sm[j] += __shfl_xor(sm[j], 4);
    sm[j] += __shfl_xor(sm[j], 8);
  }
  __syncthreads();

  f32x4 o[4] = {};
#pragma unroll
  for (int step = 0; step < 4; ++step) {
    bf16x8 pf = *(const bf16x8*)(ps + colL * 272 + (step << 6) + (g << 4));
#pragma unroll
    for (int dt = 0; dt < 4; ++dt) {
      int r = (dt << 4) + colL;
      int slot = (step << 2) + g;
      bf16x8 vf = *(const bf16x8*)(Vs + r * 256 + ((slot ^ (r & 7)) << 4));
      o[dt] = MFMA16(pf, vf, o[dt]);
    }
  }

  float rinv[4];
#pragma unroll
  for (int j = 0; j < 4; ++j) rinv[j] = 1.0f / sm[j];
#pragma unroll
  for (int dt = 0; dt < 4; ++dt) {
#pragma unroll
    for (int j = 0; j < 4; ++j) {
      const int t = qb * 64 + (w << 4) + (g << 2) + j;
      Ob[((size_t)b * 2048 + t) * 1024 + h * 64 + (dt << 4) + colL] =
          (__bf16)(o[dt][j] * rinv[j]);
    }
  }
}

extern "C" void kernel_launch(void* const* d_in, const int* in_sizes, int n_in,
                              void* d_out, int out_size, void* d_ws, size_t ws_size,
                              hipStream_t stream) {
  const float* x = (const float*)d_in[0];     // [2,2048,1024]
  const float* Wqkv = (const float*)d_in[1];  // [3072,1024]
  const float* bqkv = (const float*)d_in[2];  // [3072]
  const float* Wout = (const float*)d_in[3];  // [1024,1024]
  const float* bout = (const float*)d_in[4];  // [1024]
  float* out = (float*)d_out;                 // [2,2048,1024] fp32

  __bf16* xb = (__bf16*)d_ws;             // 4194304
  __bf16* Wqkvb = xb + 4194304;           // 3145728
  __bf16* Woutb = Wqkvb + 3145728;        // 1048576
  __bf16* Qb = Woutb + 1048576;           // 4194304 each: [B,H,2048,64]
  __bf16* Kb = Qb + 4194304;
  __bf16* Vtb = Kb + 4194304;             // [B,H,64,2048] (written transposed by gemm)
  __bf16* AOb = Vtb + 4194304;            // attn out [B,2048,1024]

  cvt3<<<4096, 256, 0, stream>>>(x, Wqkv, Wout, xb, Wqkvb, Woutb);
  gemm_qkv<<<768, 256, 0, stream>>>(xb, Wqkvb, bqkv, Qb, Kb, Vtb);
  attn_win<<<1024, 256, 0, stream>>>(Qb, Kb, Vtb, AOb);
  gemm_out<<<512, 256, 0, stream>>>(AOb, Woutb, bout, out);
}